// Round 8
// baseline (1874.006 us; speedup 1.0000x reference)
//
#include <hip/hip_runtime.h>
#include <hip/hip_bf16.h>

#define DEV __device__ __forceinline__

typedef unsigned short u16;
typedef unsigned int u32;

constexpr float INV_C  = 0.17677669529663687f;   // 1/sqrt(32)
constexpr float INV_S3 = 0.5773502691896258f;    // 1/sqrt(3)

DEV float bf2f(u32 h) { return __uint_as_float(h << 16); }
DEV u32 f2bf_bits(float f) {
  u32 u = __float_as_uint(f);
  u += 0x7fffu + ((u >> 16) & 1u);
  return u >> 16;
}

DEV void ld32f(const float* __restrict__ p, float o[32]) {
#pragma unroll
  for (int i = 0; i < 8; ++i) {
    float4 q = reinterpret_cast<const float4*>(p)[i];
    o[4*i+0]=q.x; o[4*i+1]=q.y; o[4*i+2]=q.z; o[4*i+3]=q.w;
  }
}
DEV void st32f(float* __restrict__ p, const float o[32]) {
#pragma unroll
  for (int i = 0; i < 8; ++i) {
    float4 q; q.x=o[4*i+0]; q.y=o[4*i+1]; q.z=o[4*i+2]; q.w=o[4*i+3];
    reinterpret_cast<float4*>(p)[i] = q;
  }
}
DEV void ld32h(const u16* __restrict__ p, float o[32]) {
#pragma unroll
  for (int i = 0; i < 4; ++i) {
    uint4 q = reinterpret_cast<const uint4*>(p)[i];
    u32 w0=q.x, w1=q.y, w2=q.z, w3=q.w;
    o[8*i+0]=bf2f(w0 & 0xffffu); o[8*i+1]=bf2f(w0 >> 16);
    o[8*i+2]=bf2f(w1 & 0xffffu); o[8*i+3]=bf2f(w1 >> 16);
    o[8*i+4]=bf2f(w2 & 0xffffu); o[8*i+5]=bf2f(w2 >> 16);
    o[8*i+6]=bf2f(w3 & 0xffffu); o[8*i+7]=bf2f(w3 >> 16);
  }
}
DEV void st32h(u16* __restrict__ p, const float o[32]) {
#pragma unroll
  for (int i = 0; i < 16; ++i) {
    reinterpret_cast<u32*>(p)[i] = f2bf_bits(o[2*i]) | (f2bf_bits(o[2*i+1]) << 16);
  }
}

template<bool BF>
DEV void ld_scr(const void* __restrict__ ws, size_t off, float o[32]) {
  if (BF) ld32h((const u16*)ws + off, o);
  else    ld32f((const float*)ws + off, o);
}
template<bool BF>
DEV void st_scr(void* __restrict__ ws, size_t off, const float v[32]) {
  if (BF) st32h((u16*)ws + off, v);
  else    st32f((float*)ws + off, v);
}

// out[d] (+)= INV_C * sum_c in[c] * W[c*32+d]   (weights via SGPR path)
template<bool ACC>
DEV void linT(const float* __restrict__ W, const float in[32], float out[32]) {
  float acc[32];
#pragma unroll
  for (int d = 0; d < 32; ++d) acc[d] = 0.f;
#pragma unroll 4
  for (int c = 0; c < 32; ++c) {
    const float ic = in[c];
#pragma unroll
    for (int d = 0; d < 32; ++d) acc[d] = __builtin_fmaf(ic, W[c*32+d], acc[d]);
  }
#pragma unroll
  for (int d = 0; d < 32; ++d) out[d] = ACC ? __builtin_fmaf(acc[d], INV_C, out[d]) : acc[d]*INV_C;
}
// out[u] = INV_C * sum_v in[v] * W[u*32+v]
DEV void linN(const float* __restrict__ W, const float in[32], float out[32]) {
#pragma unroll 4
  for (int u = 0; u < 32; ++u) {
    float a = 0.f;
#pragma unroll
    for (int v = 0; v < 32; ++v) a = __builtin_fmaf(in[v], W[u*32+v], a);
    out[u] = a * INV_C;
  }
}

DEV float sigmoidf(float x) { return 1.f / (1.f + __expf(-x)); }

// Resblock (node kernel path), wave0 = scalar row, waves1..3 = vector comps.
DEV void resblock_g(int wave, int lane, const float* __restrict__ W7,
                    const float in[32], float out[32], float* gsh) {
  float t1[32];
  linT<false>(W7 + (wave==0 ? 0 : 1)*1024, in, t1);     // s1 / v1
  linT<false>(W7 + (wave==0 ? 5 : 6)*1024, in, out);    // skip
  __syncthreads();                                      // barrier #1
  float t2[32];
  if (wave == 0) {
    float g[32];
    linT<false>(W7 + 2*1024, t1, g);                    // gate pre-act
#pragma unroll
    for (int c = 0; c < 32; ++c) gsh[lane*33+c] = sigmoidf(g[c]);
#pragma unroll
    for (int c = 0; c < 32; ++c) t2[c] = t1[c] * sigmoidf(t1[c]);   // silu
  }
  __syncthreads();                                      // barrier #2
  if (wave != 0) {
#pragma unroll
    for (int c = 0; c < 32; ++c) t2[c] = t1[c] * gsh[lane*33+c];
  }
  linT<true>(W7 + (wave==0 ? 3 : 4)*1024, t2, out);     // lin2 accumulate
}

// ---- interleaved-pair LDS mat-vecs (edge kernel) ----
// Pair layout: float idx = c*64 + i*8 + grp*4 + j  (grp: 0=s-matrix, 1=v-matrix).
// s-lanes (grp4=0) and v-lanes (grp4=4) read ADJACENT bank-quads -> conflict-free.
template<bool ACC>
DEV void matWi(const float* W, int grp4, const float in[32], float out[32]) {
  float acc[32];
#pragma unroll
  for (int d = 0; d < 32; ++d) acc[d] = 0.f;
#pragma unroll 2
  for (int c = 0; c < 32; ++c) {
    const float ic = in[c];
#pragma unroll
    for (int i = 0; i < 8; ++i) {
      float4 w = *reinterpret_cast<const float4*>(&W[c*64 + i*8 + grp4]);
      acc[4*i+0] = __builtin_fmaf(ic, w.x, acc[4*i+0]);
      acc[4*i+1] = __builtin_fmaf(ic, w.y, acc[4*i+1]);
      acc[4*i+2] = __builtin_fmaf(ic, w.z, acc[4*i+2]);
      acc[4*i+3] = __builtin_fmaf(ic, w.w, acc[4*i+3]);
    }
  }
#pragma unroll
  for (int d = 0; d < 32; ++d)
    out[d] = ACC ? __builtin_fmaf(acc[d], INV_C, out[d]) : acc[d]*INV_C;
}
// dual interleaved: o1 = Wa^T in, o2 = Wb^T in (both * INV_C), one pass over in
DEV void matW2i(const float* Wa, const float* Wb, int grp4, const float in[32],
                float o1[32], float o2[32]) {
  float a1[32], a2[32];
#pragma unroll
  for (int d = 0; d < 32; ++d) { a1[d] = 0.f; a2[d] = 0.f; }
#pragma unroll 2
  for (int c = 0; c < 32; ++c) {
    const float ic = in[c];
#pragma unroll
    for (int i = 0; i < 8; ++i) {
      float4 w = *reinterpret_cast<const float4*>(&Wa[c*64 + i*8 + grp4]);
      a1[4*i+0] = __builtin_fmaf(ic, w.x, a1[4*i+0]);
      a1[4*i+1] = __builtin_fmaf(ic, w.y, a1[4*i+1]);
      a1[4*i+2] = __builtin_fmaf(ic, w.z, a1[4*i+2]);
      a1[4*i+3] = __builtin_fmaf(ic, w.w, a1[4*i+3]);
    }
#pragma unroll
    for (int i = 0; i < 8; ++i) {
      float4 w = *reinterpret_cast<const float4*>(&Wb[c*64 + i*8 + grp4]);
      a2[4*i+0] = __builtin_fmaf(ic, w.x, a2[4*i+0]);
      a2[4*i+1] = __builtin_fmaf(ic, w.y, a2[4*i+1]);
      a2[4*i+2] = __builtin_fmaf(ic, w.z, a2[4*i+2]);
      a2[4*i+3] = __builtin_fmaf(ic, w.w, a2[4*i+3]);
    }
  }
#pragma unroll
  for (int d = 0; d < 32; ++d) { o1[d] = a1[d]*INV_C; o2[d] = a2[d]*INV_C; }
}
// plain-layout LDS matvec (gate; uniform address among active lanes)
template<bool ACC>
DEV void matW(const float* W, const float in[32], float out[32]) {
  float acc[32];
#pragma unroll
  for (int d = 0; d < 32; ++d) acc[d] = 0.f;
#pragma unroll 2
  for (int c = 0; c < 32; ++c) {
    const float ic = in[c];
#pragma unroll
    for (int i = 0; i < 8; ++i) {
      float4 w = *reinterpret_cast<const float4*>(&W[c*32 + i*4]);
      acc[4*i+0] = __builtin_fmaf(ic, w.x, acc[4*i+0]);
      acc[4*i+1] = __builtin_fmaf(ic, w.y, acc[4*i+1]);
      acc[4*i+2] = __builtin_fmaf(ic, w.z, acc[4*i+2]);
      acc[4*i+3] = __builtin_fmaf(ic, w.w, acc[4*i+3]);
    }
  }
#pragma unroll
  for (int d = 0; d < 32; ++d)
    out[d] = ACC ? __builtin_fmaf(acc[d], INV_C, out[d]) : acc[d]*INV_C;
}

// ====================== node kernel (unchanged) ======================
template<bool BF>
__global__ __launch_bounds__(256, 2) void node_kernel(
    const float* __restrict__ node_s, const float* __restrict__ node_v,
    const float* __restrict__ tpw, const float* __restrict__ resw,
    void* __restrict__ wsN,
    float* __restrict__ dgs, float* __restrict__ dgv, int N)
{
  __shared__ float comm[6336];
  float* gsh = comm;
  const int lane = threadIdx.x & 63;
  const int wave = threadIdx.x >> 6;
  const int job  = blockIdx.x & 1;
  const int nblk = (blockIdx.x >> 1) * 64;
  const int n = nblk + lane;
  const bool active = n < N;
  const int nrows = (N - nblk < 64) ? (N - nblk) : 64;

  const float* Wtp0 = tpw;
  const float* Wtp1 = tpw + 4096;

  {
    const float4* s4 = reinterpret_cast<const float4*>(node_v + (size_t)nblk*96);
    int tot4 = nrows * 24;
    for (int i = threadIdx.x; i < tot4; i += 256) {
      int node = (4*i)/96; int r = 4*i - node*96;
      float4 q = s4[i];
      float* dp = &comm[node*97 + r];
      dp[0]=q.x; dp[1]=q.y; dp[2]=q.z; dp[3]=q.w;
    }
  }
  __syncthreads();

  float feat[32];
  if (wave == 0) {
    if (active) ld32f(node_s + (size_t)n*32, feat);
    else {
#pragma unroll
      for (int c = 0; c < 32; ++c) feat[c] = 0.f;
    }
  } else {
    const int x = wave - 1;
    if (active) {
#pragma unroll
      for (int c = 0; c < 32; ++c) feat[c] = comm[lane*97 + 3*c + x];
    } else {
#pragma unroll
      for (int c = 0; c < 32; ++c) feat[c] = 0.f;
    }
  }
  __syncthreads();

  if (job == 0) {
    float dsv[32];
    resblock_g(wave, lane, resw + 3*7168, feat, dsv, gsh);
    __syncthreads();

    float tpo[32];
    if (wave != 0) {
      const int x = wave - 1;
      float vr1[32];
      linN(Wtp0 + 1*1024, feat, vr1);
#pragma unroll
      for (int c = 0; c < 32; ++c) comm[x*2112 + lane*33 + c] = dsv[c]*vr1[c];
    }
    __syncthreads();
    if (wave == 0) {
      float sr0[32];
      linN(Wtp0 + 0*1024, feat, sr0);
#pragma unroll
      for (int c = 0; c < 32; ++c) {
        float a = comm[0*2112+lane*33+c] + comm[1*2112+lane*33+c] + comm[2*2112+lane*33+c];
        tpo[c] = dsv[c]*sr0[c] + a*INV_S3;
      }
      float sr3[32];
      linN(Wtp0 + 3*1024, feat, sr3);
#pragma unroll
      for (int c = 0; c < 32; ++c) comm[0*2112+lane*33+c] = dsv[c];
#pragma unroll
      for (int c = 0; c < 32; ++c) comm[1*2112+lane*33+c] = sr3[c];
    }
    __syncthreads();
    if (wave != 0) {
      float vr2[32];
      linN(Wtp0 + 2*1024, feat, vr2);
#pragma unroll
      for (int c = 0; c < 32; ++c)
        tpo[c] = comm[lane*33+c]*vr2[c] + dsv[c]*comm[2112+lane*33+c];
    }

    float eo[32];
    resblock_g(wave, lane, resw + 4*7168, tpo, eo, gsh);
    {
      float qo[32];
      resblock_g(wave, lane, resw + 5*7168, feat, qo, gsh);
#pragma unroll
      for (int c = 0; c < 32; ++c) eo[c] += qo[c];
    }
    __syncthreads();

    if (wave == 0) {
      if (active) st32f(dgs + (size_t)n*32, eo);
    } else {
      const int x = wave - 1;
#pragma unroll
      for (int c = 0; c < 32; ++c) comm[lane*97 + 3*c + x] = eo[c];
    }
    __syncthreads();
    {
      float4* d4 = reinterpret_cast<float4*>(dgv + (size_t)nblk*96);
      int tot4 = nrows * 24;
      for (int i = threadIdx.x; i < tot4; i += 256) {
        int node = (4*i)/96; int r = 4*i - node*96;
        const float* sp = &comm[node*97 + r];
        float4 q; q.x=sp[0]; q.y=sp[1]; q.z=sp[2]; q.w=sp[3];
        d4[i] = q;
      }
    }
  } else {
    const size_t base = (size_t)n * 512;
    {
      float ao[32];
      resblock_g(wave, lane, resw + 0*7168, feat, ao, gsh);
      if (active) {
        if (wave == 0) st_scr<BF>(wsN, base + 0, ao);
        else           st_scr<BF>(wsN, base + 32 + (size_t)(wave-1)*32, ao);
      }
    }
    {
      float ao[32];
      resblock_g(wave, lane, resw + 2*7168, feat, ao, gsh);
      if (active) {
        if (wave == 0) st_scr<BF>(wsN, base + 128, ao);
        else           st_scr<BF>(wsN, base + 160 + (size_t)(wave-1)*32, ao);
      }
    }
    {
      float b[32];
      if (wave == 0) {
        linN(Wtp1 + 0*1024, feat, b);
        if (active) st_scr<BF>(wsN, base + 256, b);
        linN(Wtp1 + 3*1024, feat, b);
        if (active) st_scr<BF>(wsN, base + 480, b);
      } else {
        const size_t x = wave - 1;
        linN(Wtp1 + 1*1024, feat, b);
        if (active) st_scr<BF>(wsN, base + 288 + x*32, b);
        linN(Wtp1 + 2*1024, feat, b);
        if (active) st_scr<BF>(wsN, base + 384 + x*32, b);
      }
    }
  }
}

// ============ edge kernel: wave-private, interleaved LDS weights ============
// lane = (edge, comp): comp = lane&3 (0=scalar, 1..3 = x,y,z), 16 edges/wave.
// Weight pairs interleaved in LDS so s-lanes/v-lanes hit adjacent bank-quads.
// offv staged through wave-private LDS -> coalesced float4 stores.
__global__ __launch_bounds__(256, 3) void edge_kernel_f32(
    const int* __restrict__ ei, const float* __restrict__ resw,
    const float* __restrict__ wsN,
    float* __restrict__ offs, float* __restrict__ offv, int E, int ntiles)
{
  __shared__ float wsh[7168];    // pairA@0, pairL2@2048, pairSk@4096, gate@6144
  __shared__ float vst[6208];    // 4 waves x [16][97] offv staging
  {
    const float4* s4 = reinterpret_cast<const float4*>(resw + 7168);
    float4* d4 = reinterpret_cast<float4*>(wsh);
    for (int s = threadIdx.x; s < 1792; s += 256) {
      float4 v;
      if (s < 1536) {
        int pair = s >> 9, slot = s & 511;
        int grp = slot & 1, i = (slot >> 1) & 7, c = slot >> 4;
        int mat = (pair == 0) ? grp : (pair == 1) ? 3 + grp : 5 + grp;
        v = s4[mat*256 + c*8 + i];
      } else {
        v = s4[2*256 + (s - 1536)];   // gate
      }
      d4[s] = v;
    }
  }
  __syncthreads();   // the only barrier

  const int lane = threadIdx.x & 63;
  const int wave = threadIdx.x >> 6;
  const int comp = lane & 3;
  const int eloc = lane >> 2;
  const bool is_s = (comp == 0);
  const int x = comp - 1;            // valid for v-lanes
  const int grp4 = is_s ? 0 : 4;

  const float* PA = wsh;             // (s1 | v1) interleaved
  const float* PL = wsh + 2048;      // (l2s | l2v)
  const float* PS = wsh + 4096;      // (sks | skv)
  const float* W2 = wsh + 6144;      // gate, plain

  float* vbuf = vst + wave*1552;     // [16][97]

  const int wid = blockIdx.x*4 + wave;
  const int wstride = gridDim.x*4;

  for (int tile = wid; tile < ntiles; tile += wstride) {
    const int e = tile*16 + eloc;
    const bool eact = e < E;
    const int ec = eact ? e : (E - 1);
    const int sn = ei[ec], dn = ei[(size_t)E + ec];
    const float* S = wsN + (size_t)sn * 512;
    const float* D = wsN + (size_t)dn * 512;

    // ---- TP combine ----
    float t[32];
    {
      const float4* a4 = reinterpret_cast<const float4*>(D);                 // A_s[dst]
      const float4* b4 = reinterpret_cast<const float4*>(
          is_s ? S + 256 : S + 384 + (size_t)x*32);                          // B0 | Vr2_x
#pragma unroll
      for (int i = 0; i < 8; ++i) {
        float4 a = a4[i], b = b4[i];
        t[4*i+0] = a.x*b.x; t[4*i+1] = a.y*b.y; t[4*i+2] = a.z*b.z; t[4*i+3] = a.w*b.w;
      }
    }
#pragma unroll
    for (int xx = 0; xx < 3; ++xx) {
      if (is_s || comp == xx+1) {
        const float4* a4 = reinterpret_cast<const float4*>(D + 32 + xx*32);  // A_v[dst][xx]
        const float4* b4 = reinterpret_cast<const float4*>(
            is_s ? S + 288 + xx*32 : S + 480);                               // Vr1_xx | B3
        const float sc = is_s ? INV_S3 : 1.f;
#pragma unroll
        for (int i = 0; i < 8; ++i) {
          float4 a = a4[i], b = b4[i];
          t[4*i+0] = __builtin_fmaf(a.x*sc, b.x, t[4*i+0]);
          t[4*i+1] = __builtin_fmaf(a.y*sc, b.y, t[4*i+1]);
          t[4*i+2] = __builtin_fmaf(a.z*sc, b.z, t[4*i+2]);
          t[4*i+3] = __builtin_fmaf(a.w*sc, b.w, t[4*i+3]);
        }
      }
    }

    // ---- resblock res_w[1] ----
    float t1[32], o[32];
    matW2i(PA, PS, grp4, t, t1, o);      // t1 = s1|v1, o = skip

    float sg[32];
    if (is_s) {
      float g[32];
      matW<false>(W2, t1, g);
#pragma unroll
      for (int c = 0; c < 32; ++c) sg[c] = sigmoidf(g[c]);
    } else {
#pragma unroll
      for (int c = 0; c < 32; ++c) sg[c] = 0.f;
    }

    float t2[32];
    const int gsrc = lane & 60;          // comp-0 lane of this edge
#pragma unroll
    for (int c = 0; c < 32; ++c) {
      float gv = __shfl(sg[c], gsrc);
      t2[c] = is_s ? t1[c]*sigmoidf(t1[c]) : t1[c]*gv;
    }
    matWi<true>(PL, grp4, t2, o);        // o += lin2

    // ---- + R[dst] ----
    {
      const float4* r4 = reinterpret_cast<const float4*>(
          is_s ? D + 128 : D + 160 + (size_t)x*32);
#pragma unroll
      for (int i = 0; i < 8; ++i) {
        float4 r = r4[i];
        o[4*i+0] += r.x; o[4*i+1] += r.y; o[4*i+2] += r.z; o[4*i+3] += r.w;
      }
    }

    // ---- store: offs direct; offv staged through wave-private LDS ----
    if (is_s) {
      if (eact) st32f(offs + (size_t)e*32, o);
    } else {
#pragma unroll
      for (int c = 0; c < 32; ++c) vbuf[eloc*97 + 3*c + x] = o[c];
    }
    // within-wave ds_write -> ds_read: compiler inserts lgkmcnt ordering
    {
      const size_t obase = (size_t)tile * 16 * 96;
#pragma unroll
      for (int i = 0; i < 6; ++i) {
        int s = i*64 + lane;             // float4 slot in [0,384)
        int row = s / 24, c4 = s - row*24;
        const float* sp = &vbuf[row*97 + c4*4];
        float4 q; q.x = sp[0]; q.y = sp[1]; q.z = sp[2]; q.w = sp[3];
        if (tile*16 + row < E)
          *reinterpret_cast<float4*>(offv + obase + (size_t)s*4) = q;
      }
    }
  }
}

// bf16-scratch fallback edge kernel (only if ws too small for f32 scratch)
__global__ __launch_bounds__(256, 2) void edge_kernel_bf(
    const int* __restrict__ ei, const float* __restrict__ resw,
    const void* __restrict__ wsN,
    float* __restrict__ offs, float* __restrict__ offv, int E)
{
  __shared__ float smem[3104];
  const int lane = threadIdx.x & 63;
  const int wave = threadIdx.x >> 6;
  const int eblk = blockIdx.x * 64;
  const int e = eblk + lane;
  const bool active = e < E;
  const int erows = (E - eblk < 64) ? (E - eblk) : 64;
  int src = 0, dst = 0;
  if (active) { src = ei[e]; dst = ei[E + e]; }
  const size_t bs = (size_t)src * 512;
  const size_t bd = (size_t)dst * 512;

  float t[32];
  if (wave == 0) {
    float a[32], b[32];
    ld_scr<true>(wsN, bd + 0, a);
    ld_scr<true>(wsN, bs + 256, b);
#pragma unroll
    for (int c = 0; c < 32; ++c) t[c] = a[c]*b[c];
#pragma unroll
    for (int x = 0; x < 3; ++x) {
      ld_scr<true>(wsN, bd + 32 + (size_t)x*32, a);
      ld_scr<true>(wsN, bs + 288 + (size_t)x*32, b);
#pragma unroll
      for (int c = 0; c < 32; ++c) t[c] = __builtin_fmaf(a[c]*INV_S3, b[c], t[c]);
    }
  } else {
    const size_t x = wave - 1;
    float a[32], b[32];
    ld_scr<true>(wsN, bd + 0, a);
    ld_scr<true>(wsN, bs + 384 + x*32, b);
#pragma unroll
    for (int c = 0; c < 32; ++c) t[c] = a[c]*b[c];
    ld_scr<true>(wsN, bd + 32 + x*32, a);
    ld_scr<true>(wsN, bs + 480, b);
#pragma unroll
    for (int c = 0; c < 32; ++c) t[c] = __builtin_fmaf(a[c], b[c], t[c]);
  }

  float o[32];
  resblock_g(wave, lane, resw + 1*7168, t, o, smem);

  if (wave == 0) {
    float r[32];
    ld_scr<true>(wsN, bd + 128, r);
#pragma unroll
    for (int c = 0; c < 32; ++c) o[c] += r[c];
    if (active) st32f(offs + (size_t)e*32, o);
  } else {
    const int x = wave - 1;
    float r[32];
    ld_scr<true>(wsN, bd + 160 + (size_t)x*32, r);
#pragma unroll
    for (int c = 0; c < 32; ++c) o[c] += r[c];
  }
  __syncthreads();

  const int half = lane >> 5;
  const int lrow = lane & 31;
  const int rows0 = (erows < 32) ? erows : 32;
  const int rows1 = erows - rows0;

  if (wave != 0 && half == 0) {
    const int x = wave - 1;
#pragma unroll
    for (int c = 0; c < 32; ++c) smem[lrow*97 + 3*c + x] = o[c];
  }
  __syncthreads();
  {
    float4* d4 = reinterpret_cast<float4*>(offv + (size_t)eblk*96);
    int tot4 = rows0 * 24;
    for (int i = threadIdx.x; i < tot4; i += 256) {
      int row = (4*i)/96; int r = 4*i - row*96;
      const float* sp = &smem[row*97 + r];
      float4 q; q.x=sp[0]; q.y=sp[1]; q.z=sp[2]; q.w=sp[3];
      d4[i] = q;
    }
  }
  __syncthreads();
  if (wave != 0 && half == 1) {
    const int x = wave - 1;
#pragma unroll
    for (int c = 0; c < 32; ++c) smem[lrow*97 + 3*c + x] = o[c];
  }
  __syncthreads();
  if (rows1 > 0) {
    float4* d4 = reinterpret_cast<float4*>(offv + ((size_t)eblk + 32)*96);
    int tot4 = rows1 * 24;
    for (int i = threadIdx.x; i < tot4; i += 256) {
      int row = (4*i)/96; int r = 4*i - row*96;
      const float* sp = &smem[row*97 + r];
      float4 q; q.x=sp[0]; q.y=sp[1]; q.z=sp[2]; q.w=sp[3];
      d4[i] = q;
    }
  }
}

extern "C" void kernel_launch(void* const* d_in, const int* in_sizes, int n_in,
                              void* d_out, int out_size, void* d_ws, size_t ws_size,
                              hipStream_t stream) {
  const float* node_s = (const float*)d_in[0];
  const float* node_v = (const float*)d_in[1];
  const float* tpw    = (const float*)d_in[2];
  const float* resw   = (const float*)d_in[3];
  const int*   ei     = (const int*)d_in[4];
  const int N = in_sizes[0] / 32;
  const int E = in_sizes[4] / 2;

  float* out  = (float*)d_out;
  float* dgs  = out;
  float* dgv  = out + (size_t)N*32;
  float* offs = out + (size_t)N*128;
  float* offv = offs + (size_t)E*32;

  const size_t need_f32 = (size_t)N * 512 * sizeof(float);
  const int nodeGrid = 2 * ((N + 63) / 64);
  const int ntiles = (E + 15) / 16;

  if (ws_size >= need_f32) {
    node_kernel<false><<<nodeGrid, 256, 0, stream>>>(node_s, node_v, tpw, resw,
                                                     d_ws, dgs, dgv, N);
    int eg = (ntiles + 3) / 4; if (eg > 2048) eg = 2048;
    edge_kernel_f32<<<eg, 256, 0, stream>>>(ei, resw, (const float*)d_ws,
                                            offs, offv, E, ntiles);
  } else {
    node_kernel<true><<<nodeGrid, 256, 0, stream>>>(node_s, node_v, tpw, resw,
                                                    d_ws, dgs, dgv, N);
    edge_kernel_bf<<<(E + 63)/64, 256, 0, stream>>>(ei, resw, d_ws, offs, offv, E);
  }
}

// Round 9
// 1778.438 us; speedup vs baseline: 1.0537x; 1.0537x over previous
//
#include <hip/hip_runtime.h>
#include <hip/hip_bf16.h>

#define DEV __device__ __forceinline__

typedef unsigned short u16;
typedef unsigned int u32;

constexpr float INV_C  = 0.17677669529663687f;   // 1/sqrt(32)
constexpr float INV_S3 = 0.5773502691896258f;    // 1/sqrt(3)

DEV float bf2f(u32 h) { return __uint_as_float(h << 16); }
DEV u32 f2bf_bits(float f) {
  u32 u = __float_as_uint(f);
  u += 0x7fffu + ((u >> 16) & 1u);
  return u >> 16;
}

DEV void ld32f(const float* __restrict__ p, float o[32]) {
#pragma unroll
  for (int i = 0; i < 8; ++i) {
    float4 q = reinterpret_cast<const float4*>(p)[i];
    o[4*i+0]=q.x; o[4*i+1]=q.y; o[4*i+2]=q.z; o[4*i+3]=q.w;
  }
}
DEV void st32f(float* __restrict__ p, const float o[32]) {
#pragma unroll
  for (int i = 0; i < 8; ++i) {
    float4 q; q.x=o[4*i+0]; q.y=o[4*i+1]; q.z=o[4*i+2]; q.w=o[4*i+3];
    reinterpret_cast<float4*>(p)[i] = q;
  }
}
// bf16 row (32 elems = 4 uint4 loads)
DEV void ld32h(const u16* __restrict__ p, float o[32]) {
#pragma unroll
  for (int i = 0; i < 4; ++i) {
    uint4 q = reinterpret_cast<const uint4*>(p)[i];
    u32 w0=q.x, w1=q.y, w2=q.z, w3=q.w;
    o[8*i+0]=bf2f(w0 & 0xffffu); o[8*i+1]=bf2f(w0 >> 16);
    o[8*i+2]=bf2f(w1 & 0xffffu); o[8*i+3]=bf2f(w1 >> 16);
    o[8*i+4]=bf2f(w2 & 0xffffu); o[8*i+5]=bf2f(w2 >> 16);
    o[8*i+6]=bf2f(w3 & 0xffffu); o[8*i+7]=bf2f(w3 >> 16);
  }
}
DEV void st32h(u16* __restrict__ p, const float o[32]) {
#pragma unroll
  for (int i = 0; i < 16; ++i) {
    reinterpret_cast<u32*>(p)[i] = f2bf_bits(o[2*i]) | (f2bf_bits(o[2*i+1]) << 16);
  }
}

// out[d] (+)= INV_C * sum_c in[c] * W[c*32+d]   (weights via SGPR path)
template<bool ACC>
DEV void linT(const float* __restrict__ W, const float in[32], float out[32]) {
  float acc[32];
#pragma unroll
  for (int d = 0; d < 32; ++d) acc[d] = 0.f;
#pragma unroll 4
  for (int c = 0; c < 32; ++c) {
    const float ic = in[c];
#pragma unroll
    for (int d = 0; d < 32; ++d) acc[d] = __builtin_fmaf(ic, W[c*32+d], acc[d]);
  }
#pragma unroll
  for (int d = 0; d < 32; ++d) out[d] = ACC ? __builtin_fmaf(acc[d], INV_C, out[d]) : acc[d]*INV_C;
}
// out[u] = INV_C * sum_v in[v] * W[u*32+v]
DEV void linN(const float* __restrict__ W, const float in[32], float out[32]) {
#pragma unroll 4
  for (int u = 0; u < 32; ++u) {
    float a = 0.f;
#pragma unroll
    for (int v = 0; v < 32; ++v) a = __builtin_fmaf(in[v], W[u*32+v], a);
    out[u] = a * INV_C;
  }
}

DEV float sigmoidf(float x) { return 1.f / (1.f + __expf(-x)); }

// Resblock (node kernel path), wave0 = scalar row, waves1..3 = vector comps.
DEV void resblock_g(int wave, int lane, const float* __restrict__ W7,
                    const float in[32], float out[32], float* gsh) {
  float t1[32];
  linT<false>(W7 + (wave==0 ? 0 : 1)*1024, in, t1);     // s1 / v1
  linT<false>(W7 + (wave==0 ? 5 : 6)*1024, in, out);    // skip
  __syncthreads();                                      // barrier #1
  float t2[32];
  if (wave == 0) {
    float g[32];
    linT<false>(W7 + 2*1024, t1, g);                    // gate pre-act
#pragma unroll
    for (int c = 0; c < 32; ++c) gsh[lane*33+c] = sigmoidf(g[c]);
#pragma unroll
    for (int c = 0; c < 32; ++c) t2[c] = t1[c] * sigmoidf(t1[c]);   // silu
  }
  __syncthreads();                                      // barrier #2
  if (wave != 0) {
#pragma unroll
    for (int c = 0; c < 32; ++c) t2[c] = t1[c] * gsh[lane*33+c];
  }
  linT<true>(W7 + (wave==0 ? 3 : 4)*1024, t2, out);     // lin2 accumulate
}

// ---- interleaved-pair LDS mat-vecs (edge kernel) ----
template<bool ACC>
DEV void matWi(const float* W, int grp4, const float in[32], float out[32]) {
  float acc[32];
#pragma unroll
  for (int d = 0; d < 32; ++d) acc[d] = 0.f;
#pragma unroll 2
  for (int c = 0; c < 32; ++c) {
    const float ic = in[c];
#pragma unroll
    for (int i = 0; i < 8; ++i) {
      float4 w = *reinterpret_cast<const float4*>(&W[c*64 + i*8 + grp4]);
      acc[4*i+0] = __builtin_fmaf(ic, w.x, acc[4*i+0]);
      acc[4*i+1] = __builtin_fmaf(ic, w.y, acc[4*i+1]);
      acc[4*i+2] = __builtin_fmaf(ic, w.z, acc[4*i+2]);
      acc[4*i+3] = __builtin_fmaf(ic, w.w, acc[4*i+3]);
    }
  }
#pragma unroll
  for (int d = 0; d < 32; ++d)
    out[d] = ACC ? __builtin_fmaf(acc[d], INV_C, out[d]) : acc[d]*INV_C;
}
DEV void matW2i(const float* Wa, const float* Wb, int grp4, const float in[32],
                float o1[32], float o2[32]) {
  float a1[32], a2[32];
#pragma unroll
  for (int d = 0; d < 32; ++d) { a1[d] = 0.f; a2[d] = 0.f; }
#pragma unroll 2
  for (int c = 0; c < 32; ++c) {
    const float ic = in[c];
#pragma unroll
    for (int i = 0; i < 8; ++i) {
      float4 w = *reinterpret_cast<const float4*>(&Wa[c*64 + i*8 + grp4]);
      a1[4*i+0] = __builtin_fmaf(ic, w.x, a1[4*i+0]);
      a1[4*i+1] = __builtin_fmaf(ic, w.y, a1[4*i+1]);
      a1[4*i+2] = __builtin_fmaf(ic, w.z, a1[4*i+2]);
      a1[4*i+3] = __builtin_fmaf(ic, w.w, a1[4*i+3]);
    }
#pragma unroll
    for (int i = 0; i < 8; ++i) {
      float4 w = *reinterpret_cast<const float4*>(&Wb[c*64 + i*8 + grp4]);
      a2[4*i+0] = __builtin_fmaf(ic, w.x, a2[4*i+0]);
      a2[4*i+1] = __builtin_fmaf(ic, w.y, a2[4*i+1]);
      a2[4*i+2] = __builtin_fmaf(ic, w.z, a2[4*i+2]);
      a2[4*i+3] = __builtin_fmaf(ic, w.w, a2[4*i+3]);
    }
  }
#pragma unroll
  for (int d = 0; d < 32; ++d) { o1[d] = a1[d]*INV_C; o2[d] = a2[d]*INV_C; }
}
template<bool ACC>
DEV void matW(const float* W, const float in[32], float out[32]) {
  float acc[32];
#pragma unroll
  for (int d = 0; d < 32; ++d) acc[d] = 0.f;
#pragma unroll 2
  for (int c = 0; c < 32; ++c) {
    const float ic = in[c];
#pragma unroll
    for (int i = 0; i < 8; ++i) {
      float4 w = *reinterpret_cast<const float4*>(&W[c*32 + i*4]);
      acc[4*i+0] = __builtin_fmaf(ic, w.x, acc[4*i+0]);
      acc[4*i+1] = __builtin_fmaf(ic, w.y, acc[4*i+1]);
      acc[4*i+2] = __builtin_fmaf(ic, w.z, acc[4*i+2]);
      acc[4*i+3] = __builtin_fmaf(ic, w.w, acc[4*i+3]);
    }
  }
#pragma unroll
  for (int d = 0; d < 32; ++d)
    out[d] = ACC ? __builtin_fmaf(acc[d], INV_C, out[d]) : acc[d]*INV_C;
}

// ====================== node kernel (bf16 scratch stores) ======================
// Scratch per node (512 bf16): A_s@0, A_v@32+32x, R_s@128, R_v@160+32x,
//                              B0@256, Vr1@288+32x, Vr2@384+32x, B3@480
__global__ __launch_bounds__(256, 2) void node_kernel(
    const float* __restrict__ node_s, const float* __restrict__ node_v,
    const float* __restrict__ tpw, const float* __restrict__ resw,
    u16* __restrict__ wsN,
    float* __restrict__ dgs, float* __restrict__ dgv, int N)
{
  __shared__ float comm[6336];
  float* gsh = comm;
  const int lane = threadIdx.x & 63;
  const int wave = threadIdx.x >> 6;
  const int job  = blockIdx.x & 1;
  const int nblk = (blockIdx.x >> 1) * 64;
  const int n = nblk + lane;
  const bool active = n < N;
  const int nrows = (N - nblk < 64) ? (N - nblk) : 64;

  const float* Wtp0 = tpw;
  const float* Wtp1 = tpw + 4096;

  {
    const float4* s4 = reinterpret_cast<const float4*>(node_v + (size_t)nblk*96);
    int tot4 = nrows * 24;
    for (int i = threadIdx.x; i < tot4; i += 256) {
      int node = (4*i)/96; int r = 4*i - node*96;
      float4 q = s4[i];
      float* dp = &comm[node*97 + r];
      dp[0]=q.x; dp[1]=q.y; dp[2]=q.z; dp[3]=q.w;
    }
  }
  __syncthreads();

  float feat[32];
  if (wave == 0) {
    if (active) ld32f(node_s + (size_t)n*32, feat);
    else {
#pragma unroll
      for (int c = 0; c < 32; ++c) feat[c] = 0.f;
    }
  } else {
    const int x = wave - 1;
    if (active) {
#pragma unroll
      for (int c = 0; c < 32; ++c) feat[c] = comm[lane*97 + 3*c + x];
    } else {
#pragma unroll
      for (int c = 0; c < 32; ++c) feat[c] = 0.f;
    }
  }
  __syncthreads();

  if (job == 0) {
    float dsv[32];
    resblock_g(wave, lane, resw + 3*7168, feat, dsv, gsh);
    __syncthreads();

    float tpo[32];
    if (wave != 0) {
      const int x = wave - 1;
      float vr1[32];
      linN(Wtp0 + 1*1024, feat, vr1);
#pragma unroll
      for (int c = 0; c < 32; ++c) comm[x*2112 + lane*33 + c] = dsv[c]*vr1[c];
    }
    __syncthreads();
    if (wave == 0) {
      float sr0[32];
      linN(Wtp0 + 0*1024, feat, sr0);
#pragma unroll
      for (int c = 0; c < 32; ++c) {
        float a = comm[0*2112+lane*33+c] + comm[1*2112+lane*33+c] + comm[2*2112+lane*33+c];
        tpo[c] = dsv[c]*sr0[c] + a*INV_S3;
      }
      float sr3[32];
      linN(Wtp0 + 3*1024, feat, sr3);
#pragma unroll
      for (int c = 0; c < 32; ++c) comm[0*2112+lane*33+c] = dsv[c];
#pragma unroll
      for (int c = 0; c < 32; ++c) comm[1*2112+lane*33+c] = sr3[c];
    }
    __syncthreads();
    if (wave != 0) {
      float vr2[32];
      linN(Wtp0 + 2*1024, feat, vr2);
#pragma unroll
      for (int c = 0; c < 32; ++c)
        tpo[c] = comm[lane*33+c]*vr2[c] + dsv[c]*comm[2112+lane*33+c];
    }

    float eo[32];
    resblock_g(wave, lane, resw + 4*7168, tpo, eo, gsh);
    {
      float qo[32];
      resblock_g(wave, lane, resw + 5*7168, feat, qo, gsh);
#pragma unroll
      for (int c = 0; c < 32; ++c) eo[c] += qo[c];
    }
    __syncthreads();

    if (wave == 0) {
      if (active) st32f(dgs + (size_t)n*32, eo);
    } else {
      const int x = wave - 1;
#pragma unroll
      for (int c = 0; c < 32; ++c) comm[lane*97 + 3*c + x] = eo[c];
    }
    __syncthreads();
    {
      float4* d4 = reinterpret_cast<float4*>(dgv + (size_t)nblk*96);
      int tot4 = nrows * 24;
      for (int i = threadIdx.x; i < tot4; i += 256) {
        int node = (4*i)/96; int r = 4*i - node*96;
        const float* sp = &comm[node*97 + r];
        float4 q; q.x=sp[0]; q.y=sp[1]; q.z=sp[2]; q.w=sp[3];
        d4[i] = q;
      }
    }
  } else {
    const size_t base = (size_t)n * 512;
    {
      float ao[32];
      resblock_g(wave, lane, resw + 0*7168, feat, ao, gsh);
      if (active) {
        if (wave == 0) st32h(wsN + base + 0, ao);
        else           st32h(wsN + base + 32 + (size_t)(wave-1)*32, ao);
      }
    }
    {
      float ao[32];
      resblock_g(wave, lane, resw + 2*7168, feat, ao, gsh);
      if (active) {
        if (wave == 0) st32h(wsN + base + 128, ao);
        else           st32h(wsN + base + 160 + (size_t)(wave-1)*32, ao);
      }
    }
    {
      float b[32];
      if (wave == 0) {
        linN(Wtp1 + 0*1024, feat, b);
        if (active) st32h(wsN + base + 256, b);
        linN(Wtp1 + 3*1024, feat, b);
        if (active) st32h(wsN + base + 480, b);
      } else {
        const size_t x = wave - 1;
        linN(Wtp1 + 1*1024, feat, b);
        if (active) st32h(wsN + base + 288 + x*32, b);
        linN(Wtp1 + 2*1024, feat, b);
        if (active) st32h(wsN + base + 384 + x*32, b);
      }
    }
  }
}

// ============ edge kernel: wave-private, bf16 scratch gather ============
// lane = (edge, comp): comp = lane&3 (0=scalar, 1..3 = x,y,z), 16 edges/wave.
// bf16 scratch rows = 64 B -> 4 uint4 loads (4x fewer vmem instrs than f32).
__global__ __launch_bounds__(256, 3) void edge_kernel(
    const int* __restrict__ ei, const float* __restrict__ resw,
    const u16* __restrict__ wsN,
    float* __restrict__ offs, float* __restrict__ offv, int E, int ntiles)
{
  __shared__ float wsh[7168];    // pairA@0, pairL2@2048, pairSk@4096, gate@6144
  __shared__ float vst[6208];    // 4 waves x [16][97] offv staging
  {
    const float4* s4 = reinterpret_cast<const float4*>(resw + 7168);
    float4* d4 = reinterpret_cast<float4*>(wsh);
    for (int s = threadIdx.x; s < 1792; s += 256) {
      float4 v;
      if (s < 1536) {
        int pair = s >> 9, slot = s & 511;
        int grp = slot & 1, i = (slot >> 1) & 7, c = slot >> 4;
        int mat = (pair == 0) ? grp : (pair == 1) ? 3 + grp : 5 + grp;
        v = s4[mat*256 + c*8 + i];
      } else {
        v = s4[2*256 + (s - 1536)];   // gate
      }
      d4[s] = v;
    }
  }
  __syncthreads();   // the only barrier

  const int lane = threadIdx.x & 63;
  const int wave = threadIdx.x >> 6;
  const int comp = lane & 3;
  const int eloc = lane >> 2;
  const bool is_s = (comp == 0);
  const int x = comp - 1;            // valid for v-lanes
  const int grp4 = is_s ? 0 : 4;

  const float* PA = wsh;             // (s1 | v1) interleaved
  const float* PL = wsh + 2048;      // (l2s | l2v)
  const float* PS = wsh + 4096;      // (sks | skv)
  const float* W2 = wsh + 6144;      // gate, plain

  float* vbuf = vst + wave*1552;     // [16][97]

  const int wid = blockIdx.x*4 + wave;
  const int wstride = gridDim.x*4;

  for (int tile = wid; tile < ntiles; tile += wstride) {
    const int e = tile*16 + eloc;
    const bool eact = e < E;
    const int ec = eact ? e : (E - 1);
    const int sn = ei[ec], dn = ei[(size_t)E + ec];
    const u16* S = wsN + (size_t)sn * 512;
    const u16* D = wsN + (size_t)dn * 512;

    // ---- TP combine (bf16 rows) ----
    float t[32];
    {
      float a[32], b[32];
      ld32h(D, a);                                        // A_s[dst]
      ld32h(is_s ? S + 256 : S + 384 + (size_t)x*32, b);  // B0 | Vr2_x
#pragma unroll
      for (int c = 0; c < 32; ++c) t[c] = a[c]*b[c];
    }
#pragma unroll
    for (int xx = 0; xx < 3; ++xx) {
      if (is_s || comp == xx+1) {
        float a[32], b[32];
        ld32h(D + 32 + xx*32, a);                         // A_v[dst][xx]
        ld32h(is_s ? S + 288 + xx*32 : S + 480, b);       // Vr1_xx | B3
        const float sc = is_s ? INV_S3 : 1.f;
#pragma unroll
        for (int c = 0; c < 32; ++c) t[c] = __builtin_fmaf(a[c]*sc, b[c], t[c]);
      }
    }

    // ---- resblock res_w[1] ----
    float t1[32], o[32];
    matW2i(PA, PS, grp4, t, t1, o);      // t1 = s1|v1, o = skip

    float sg[32];
    if (is_s) {
      float g[32];
      matW<false>(W2, t1, g);
#pragma unroll
      for (int c = 0; c < 32; ++c) sg[c] = sigmoidf(g[c]);
    } else {
#pragma unroll
      for (int c = 0; c < 32; ++c) sg[c] = 0.f;
    }

    float t2[32];
    const int gsrc = lane & 60;          // comp-0 lane of this edge
#pragma unroll
    for (int c = 0; c < 32; ++c) {
      float gv = __shfl(sg[c], gsrc);
      t2[c] = is_s ? t1[c]*sigmoidf(t1[c]) : t1[c]*gv;
    }
    matWi<true>(PL, grp4, t2, o);        // o += lin2

    // ---- + R[dst] (R_s@128, R_v@160+32x -> contiguous per comp) ----
    {
      float r[32];
      ld32h(D + 128 + comp*32, r);
#pragma unroll
      for (int c = 0; c < 32; ++c) o[c] += r[c];
    }

    // ---- store: offs direct; offv staged through wave-private LDS ----
    if (is_s) {
      if (eact) st32f(offs + (size_t)e*32, o);
    } else {
#pragma unroll
      for (int c = 0; c < 32; ++c) vbuf[eloc*97 + 3*c + x] = o[c];
    }
    {
      const size_t obase = (size_t)tile * 16 * 96;
#pragma unroll
      for (int i = 0; i < 6; ++i) {
        int s = i*64 + lane;             // float4 slot in [0,384)
        int row = s / 24, c4 = s - row*24;
        const float* sp = &vbuf[row*97 + c4*4];
        float4 q; q.x = sp[0]; q.y = sp[1]; q.z = sp[2]; q.w = sp[3];
        if (tile*16 + row < E)
          *reinterpret_cast<float4*>(offv + obase + (size_t)s*4) = q;
      }
    }
  }
}

extern "C" void kernel_launch(void* const* d_in, const int* in_sizes, int n_in,
                              void* d_out, int out_size, void* d_ws, size_t ws_size,
                              hipStream_t stream) {
  const float* node_s = (const float*)d_in[0];
  const float* node_v = (const float*)d_in[1];
  const float* tpw    = (const float*)d_in[2];
  const float* resw   = (const float*)d_in[3];
  const int*   ei     = (const int*)d_in[4];
  const int N = in_sizes[0] / 32;
  const int E = in_sizes[4] / 2;

  float* out  = (float*)d_out;
  float* dgs  = out;
  float* dgv  = out + (size_t)N*32;
  float* offs = out + (size_t)N*128;
  float* offv = offs + (size_t)E*32;

  u16* wsB = (u16*)d_ws;               // bf16 scratch: N*512*2 bytes (~51 MB)

  const int nodeGrid = 2 * ((N + 63) / 64);
  const int ntiles = (E + 15) / 16;

  node_kernel<<<nodeGrid, 256, 0, stream>>>(node_s, node_v, tpw, resw,
                                            wsB, dgs, dgv, N);
  int eg = (ntiles + 3) / 4; if (eg > 2048) eg = 2048;
  edge_kernel<<<eg, 256, 0, stream>>>(ei, resw, wsB, offs, offv, E, ntiles);
}

// Round 10
// 1049.137 us; speedup vs baseline: 1.7862x; 1.6951x over previous
//
#include <hip/hip_runtime.h>
#include <hip/hip_bf16.h>

#define DEV __device__ __forceinline__

typedef unsigned short u16;
typedef unsigned int u32;

typedef __attribute__((ext_vector_type(8))) short bf16x8;   // 8 bf16 (4 VGPRs)
typedef __attribute__((ext_vector_type(4))) float f32x4;

constexpr float INV_C  = 0.17677669529663687f;   // 1/sqrt(32)
constexpr float INV_S3 = 0.5773502691896258f;    // 1/sqrt(3)

DEV float bf2f(u32 h) { return __uint_as_float(h << 16); }
DEV u32 f2bf_bits(float f) {
  u32 u = __float_as_uint(f);
  u += 0x7fffu + ((u >> 16) & 1u);
  return u >> 16;
}

DEV void ld32f(const float* __restrict__ p, float o[32]) {
#pragma unroll
  for (int i = 0; i < 8; ++i) {
    float4 q = reinterpret_cast<const float4*>(p)[i];
    o[4*i+0]=q.x; o[4*i+1]=q.y; o[4*i+2]=q.z; o[4*i+3]=q.w;
  }
}
DEV void st32f(float* __restrict__ p, const float o[32]) {
#pragma unroll
  for (int i = 0; i < 8; ++i) {
    float4 q; q.x=o[4*i+0]; q.y=o[4*i+1]; q.z=o[4*i+2]; q.w=o[4*i+3];
    reinterpret_cast<float4*>(p)[i] = q;
  }
}
DEV void ld32h(const u16* __restrict__ p, float o[32]) {
#pragma unroll
  for (int i = 0; i < 4; ++i) {
    uint4 q = reinterpret_cast<const uint4*>(p)[i];
    u32 w0=q.x, w1=q.y, w2=q.z, w3=q.w;
    o[8*i+0]=bf2f(w0 & 0xffffu); o[8*i+1]=bf2f(w0 >> 16);
    o[8*i+2]=bf2f(w1 & 0xffffu); o[8*i+3]=bf2f(w1 >> 16);
    o[8*i+4]=bf2f(w2 & 0xffffu); o[8*i+5]=bf2f(w2 >> 16);
    o[8*i+6]=bf2f(w3 & 0xffffu); o[8*i+7]=bf2f(w3 >> 16);
  }
}
DEV void st32h(u16* __restrict__ p, const float o[32]) {
#pragma unroll
  for (int i = 0; i < 16; ++i) {
    reinterpret_cast<u32*>(p)[i] = f2bf_bits(o[2*i]) | (f2bf_bits(o[2*i+1]) << 16);
  }
}
// 8-element bf16 slice (16 B, aligned)
DEV void ld8h(const u16* __restrict__ p, float o[8]) {
  uint4 q = *reinterpret_cast<const uint4*>(p);
  o[0]=bf2f(q.x & 0xffffu); o[1]=bf2f(q.x >> 16);
  o[2]=bf2f(q.y & 0xffffu); o[3]=bf2f(q.y >> 16);
  o[4]=bf2f(q.z & 0xffffu); o[5]=bf2f(q.z >> 16);
  o[6]=bf2f(q.w & 0xffffu); o[7]=bf2f(q.w >> 16);
}
DEV bf16x8 cvt8(const float t[8]) {
  bf16x8 r;
#pragma unroll
  for (int j = 0; j < 8; ++j) r[j] = (short)f2bf_bits(t[j]);
  return r;
}

DEV f32x4 mfma16(bf16x8 a, bf16x8 b, f32x4 c) {
  return __builtin_amdgcn_mfma_f32_16x16x32_bf16(a, b, c, 0, 0, 0);
}

// B-fragment: lane holds B[k=(kg*8+j)][n=colbase], W layout W[c][d] (k=c)
DEV bf16x8 ldBfrag(const float* __restrict__ W, int kg, int colbase) {
  bf16x8 r;
#pragma unroll
  for (int j = 0; j < 8; ++j)
    r[j] = (short)f2bf_bits(W[(kg*8 + j)*32 + colbase]);
  return r;
}

// out[d] (+)= INV_C * sum_c in[c] * W[c*32+d]  (node kernel, SGPR weights)
template<bool ACC>
DEV void linT(const float* __restrict__ W, const float in[32], float out[32]) {
  float acc[32];
#pragma unroll
  for (int d = 0; d < 32; ++d) acc[d] = 0.f;
#pragma unroll 4
  for (int c = 0; c < 32; ++c) {
    const float ic = in[c];
#pragma unroll
    for (int d = 0; d < 32; ++d) acc[d] = __builtin_fmaf(ic, W[c*32+d], acc[d]);
  }
#pragma unroll
  for (int d = 0; d < 32; ++d) out[d] = ACC ? __builtin_fmaf(acc[d], INV_C, out[d]) : acc[d]*INV_C;
}
DEV void linN(const float* __restrict__ W, const float in[32], float out[32]) {
#pragma unroll 4
  for (int u = 0; u < 32; ++u) {
    float a = 0.f;
#pragma unroll
    for (int v = 0; v < 32; ++v) a = __builtin_fmaf(in[v], W[u*32+v], a);
    out[u] = a * INV_C;
  }
}

DEV float sigmoidf(float x) { return 1.f / (1.f + __expf(-x)); }

DEV void resblock_g(int wave, int lane, const float* __restrict__ W7,
                    const float in[32], float out[32], float* gsh) {
  float t1[32];
  linT<false>(W7 + (wave==0 ? 0 : 1)*1024, in, t1);     // s1 / v1
  linT<false>(W7 + (wave==0 ? 5 : 6)*1024, in, out);    // skip
  __syncthreads();                                      // barrier #1
  float t2[32];
  if (wave == 0) {
    float g[32];
    linT<false>(W7 + 2*1024, t1, g);                    // gate pre-act
#pragma unroll
    for (int c = 0; c < 32; ++c) gsh[lane*33+c] = sigmoidf(g[c]);
#pragma unroll
    for (int c = 0; c < 32; ++c) t2[c] = t1[c] * sigmoidf(t1[c]);   // silu
  }
  __syncthreads();                                      // barrier #2
  if (wave != 0) {
#pragma unroll
    for (int c = 0; c < 32; ++c) t2[c] = t1[c] * gsh[lane*33+c];
  }
  linT<true>(W7 + (wave==0 ? 3 : 4)*1024, t2, out);     // lin2 accumulate
}

// ====================== node kernel (unchanged from round 9) ======================
__global__ __launch_bounds__(256, 2) void node_kernel(
    const float* __restrict__ node_s, const float* __restrict__ node_v,
    const float* __restrict__ tpw, const float* __restrict__ resw,
    u16* __restrict__ wsN,
    float* __restrict__ dgs, float* __restrict__ dgv, int N)
{
  __shared__ float comm[6336];
  float* gsh = comm;
  const int lane = threadIdx.x & 63;
  const int wave = threadIdx.x >> 6;
  const int job  = blockIdx.x & 1;
  const int nblk = (blockIdx.x >> 1) * 64;
  const int n = nblk + lane;
  const bool active = n < N;
  const int nrows = (N - nblk < 64) ? (N - nblk) : 64;

  const float* Wtp0 = tpw;
  const float* Wtp1 = tpw + 4096;

  {
    const float4* s4 = reinterpret_cast<const float4*>(node_v + (size_t)nblk*96);
    int tot4 = nrows * 24;
    for (int i = threadIdx.x; i < tot4; i += 256) {
      int node = (4*i)/96; int r = 4*i - node*96;
      float4 q = s4[i];
      float* dp = &comm[node*97 + r];
      dp[0]=q.x; dp[1]=q.y; dp[2]=q.z; dp[3]=q.w;
    }
  }
  __syncthreads();

  float feat[32];
  if (wave == 0) {
    if (active) ld32f(node_s + (size_t)n*32, feat);
    else {
#pragma unroll
      for (int c = 0; c < 32; ++c) feat[c] = 0.f;
    }
  } else {
    const int x = wave - 1;
    if (active) {
#pragma unroll
      for (int c = 0; c < 32; ++c) feat[c] = comm[lane*97 + 3*c + x];
    } else {
#pragma unroll
      for (int c = 0; c < 32; ++c) feat[c] = 0.f;
    }
  }
  __syncthreads();

  if (job == 0) {
    float dsv[32];
    resblock_g(wave, lane, resw + 3*7168, feat, dsv, gsh);
    __syncthreads();

    float tpo[32];
    if (wave != 0) {
      const int x = wave - 1;
      float vr1[32];
      linN(Wtp0 + 1*1024, feat, vr1);
#pragma unroll
      for (int c = 0; c < 32; ++c) comm[x*2112 + lane*33 + c] = dsv[c]*vr1[c];
    }
    __syncthreads();
    if (wave == 0) {
      float sr0[32];
      linN(Wtp0 + 0*1024, feat, sr0);
#pragma unroll
      for (int c = 0; c < 32; ++c) {
        float a = comm[0*2112+lane*33+c] + comm[1*2112+lane*33+c] + comm[2*2112+lane*33+c];
        tpo[c] = dsv[c]*sr0[c] + a*INV_S3;
      }
      float sr3[32];
      linN(Wtp0 + 3*1024, feat, sr3);
#pragma unroll
      for (int c = 0; c < 32; ++c) comm[0*2112+lane*33+c] = dsv[c];
#pragma unroll
      for (int c = 0; c < 32; ++c) comm[1*2112+lane*33+c] = sr3[c];
    }
    __syncthreads();
    if (wave != 0) {
      float vr2[32];
      linN(Wtp0 + 2*1024, feat, vr2);
#pragma unroll
      for (int c = 0; c < 32; ++c)
        tpo[c] = comm[lane*33+c]*vr2[c] + dsv[c]*comm[2112+lane*33+c];
    }

    float eo[32];
    resblock_g(wave, lane, resw + 4*7168, tpo, eo, gsh);
    {
      float qo[32];
      resblock_g(wave, lane, resw + 5*7168, feat, qo, gsh);
#pragma unroll
      for (int c = 0; c < 32; ++c) eo[c] += qo[c];
    }
    __syncthreads();

    if (wave == 0) {
      if (active) st32f(dgs + (size_t)n*32, eo);
    } else {
      const int x = wave - 1;
#pragma unroll
      for (int c = 0; c < 32; ++c) comm[lane*97 + 3*c + x] = eo[c];
    }
    __syncthreads();
    {
      float4* d4 = reinterpret_cast<float4*>(dgv + (size_t)nblk*96);
      int tot4 = nrows * 24;
      for (int i = threadIdx.x; i < tot4; i += 256) {
        int node = (4*i)/96; int r = 4*i - node*96;
        const float* sp = &comm[node*97 + r];
        float4 q; q.x=sp[0]; q.y=sp[1]; q.z=sp[2]; q.w=sp[3];
        d4[i] = q;
      }
    }
  } else {
    const size_t base = (size_t)n * 512;
    {
      float ao[32];
      resblock_g(wave, lane, resw + 0*7168, feat, ao, gsh);
      if (active) {
        if (wave == 0) st32h(wsN + base + 0, ao);
        else           st32h(wsN + base + 32 + (size_t)(wave-1)*32, ao);
      }
    }
    {
      float ao[32];
      resblock_g(wave, lane, resw + 2*7168, feat, ao, gsh);
      if (active) {
        if (wave == 0) st32h(wsN + base + 128, ao);
        else           st32h(wsN + base + 160 + (size_t)(wave-1)*32, ao);
      }
    }
    {
      float b[32];
      if (wave == 0) {
        linN(Wtp1 + 0*1024, feat, b);
        if (active) st32h(wsN + base + 256, b);
        linN(Wtp1 + 3*1024, feat, b);
        if (active) st32h(wsN + base + 480, b);
      } else {
        const size_t x = wave - 1;
        linN(Wtp1 + 1*1024, feat, b);
        if (active) st32h(wsN + base + 288 + x*32, b);
        linN(Wtp1 + 2*1024, feat, b);
        if (active) st32h(wsN + base + 384 + x*32, b);
      }
    }
  }
}

// ============ edge kernel: MFMA resblock, weights in VGPR B-fragments ============
// Per wave: 16 edges -> 64 activation rows [s, vx, vy, vz blocks of 16].
// Compute-phase lane map: row = lane&15 (edge), k-group = lane>>4.
// All linears = 8x mfma_f32_16x16x32_bf16 (4 row-tiles x 2 col-tiles).
// Gate C-frags align elementwise with v-row C-frags (same lane, same reg).
__global__ __launch_bounds__(256) void edge_kernel(
    const int* __restrict__ ei, const float* __restrict__ resw,
    const u16* __restrict__ wsN,
    float* __restrict__ offs, float* __restrict__ offv, int E, int ntiles)
{
  __shared__ __align__(16) float sbuf[9216];   // 4 waves x 2304 f32 private
  const int lane = threadIdx.x & 63;
  const int wave = threadIdx.x >> 6;
  float* wbuf = sbuf + wave*2304;

  const int col = lane & 15;
  const int kg  = lane >> 4;

  // ---- load weight B-fragments once (res_w[1]) ----
  const float* W = resw + 7168;
  bf16x8 Bs1[2], Bv1[2], Bg[2], Bl2s[2], Bl2v[2], Bsks[2], Bskv[2];
#pragma unroll
  for (int ct = 0; ct < 2; ++ct) {
    int cb = ct*16 + col;
    Bs1[ct]  = ldBfrag(W + 0*1024, kg, cb);
    Bv1[ct]  = ldBfrag(W + 1*1024, kg, cb);
    Bg[ct]   = ldBfrag(W + 2*1024, kg, cb);
    Bl2s[ct] = ldBfrag(W + 3*1024, kg, cb);
    Bl2v[ct] = ldBfrag(W + 4*1024, kg, cb);
    Bsks[ct] = ldBfrag(W + 5*1024, kg, cb);
    Bskv[ct] = ldBfrag(W + 6*1024, kg, cb);
  }

  const int wid = blockIdx.x*4 + wave;
  const int wstride = gridDim.x*4;
  const f32x4 zero4 = {0.f, 0.f, 0.f, 0.f};

  for (int tile = wid; tile < ntiles; tile += wstride) {
    // ---- gather + TP combine directly into A-fragments ----
    int e = tile*16 + col;
    int ec = (e < E) ? e : (E - 1);
    int sn = ei[ec], dn = ei[(size_t)E + ec];
    const u16* S = wsN + (size_t)sn*512 + kg*8;
    const u16* D = wsN + (size_t)dn*512 + kg*8;

    float As[8], Av0[8], Av1[8], Av2[8], b[8], acc[8], t[8];
    ld8h(D + 0,  As);
    ld8h(D + 32, Av0);
    ld8h(D + 64, Av1);
    ld8h(D + 96, Av2);

    bf16x8 tA[4];
    ld8h(S + 256, b);
#pragma unroll
    for (int j = 0; j < 8; ++j) t[j] = As[j]*b[j];
    ld8h(S + 288, b);
#pragma unroll
    for (int j = 0; j < 8; ++j) acc[j] = Av0[j]*b[j];
    ld8h(S + 320, b);
#pragma unroll
    for (int j = 0; j < 8; ++j) acc[j] = __builtin_fmaf(Av1[j], b[j], acc[j]);
    ld8h(S + 352, b);
#pragma unroll
    for (int j = 0; j < 8; ++j) acc[j] = __builtin_fmaf(Av2[j], b[j], acc[j]);
#pragma unroll
    for (int j = 0; j < 8; ++j) t[j] = __builtin_fmaf(acc[j], INV_S3, t[j]);
    tA[0] = cvt8(t);

    ld8h(S + 480, acc);                         // B3
    ld8h(S + 384, b);
#pragma unroll
    for (int j = 0; j < 8; ++j) t[j] = As[j]*b[j] + Av0[j]*acc[j];
    tA[1] = cvt8(t);
    ld8h(S + 416, b);
#pragma unroll
    for (int j = 0; j < 8; ++j) t[j] = As[j]*b[j] + Av1[j]*acc[j];
    tA[2] = cvt8(t);
    ld8h(S + 448, b);
#pragma unroll
    for (int j = 0; j < 8; ++j) t[j] = As[j]*b[j] + Av2[j]*acc[j];
    tA[3] = cvt8(t);

    // ---- matmul1 (t1) + skip (same A) ----
    f32x4 c1[8], co[8];
#pragma unroll
    for (int i = 0; i < 8; ++i) { c1[i] = zero4; co[i] = zero4; }
#pragma unroll
    for (int rt = 0; rt < 4; ++rt) {
#pragma unroll
      for (int ct = 0; ct < 2; ++ct) {
        c1[rt*2+ct] = mfma16(tA[rt], rt==0 ? Bs1[ct] : Bv1[ct], c1[rt*2+ct]);
        co[rt*2+ct] = mfma16(tA[rt], rt==0 ? Bsks[ct] : Bskv[ct], co[rt*2+ct]);
      }
    }
#pragma unroll
    for (int i = 0; i < 8; ++i) c1[i] *= INV_C;   // t1

    // ---- gate: transpose t1 s-rows (C->A via LDS), MFMA, sigmoid ----
#pragma unroll
    for (int ct = 0; ct < 2; ++ct)
#pragma unroll
      for (int i = 0; i < 4; ++i)
        wbuf[(kg*4 + i)*36 + ct*16 + col] = c1[ct][i];
    float ag[8];
    *reinterpret_cast<float4*>(&ag[0]) = *reinterpret_cast<const float4*>(&wbuf[col*36 + kg*8]);
    *reinterpret_cast<float4*>(&ag[4]) = *reinterpret_cast<const float4*>(&wbuf[col*36 + kg*8 + 4]);
    bf16x8 Ag = cvt8(ag);
    f32x4 cg0 = mfma16(Ag, Bg[0], zero4);
    f32x4 cg1 = mfma16(Ag, Bg[1], zero4);
    float g0[4], g1[4];
#pragma unroll
    for (int i = 0; i < 4; ++i) {
      g0[i] = sigmoidf(cg0[i]*INV_C);
      g1[i] = sigmoidf(cg1[i]*INV_C);
    }

    // ---- t2 in C-layout: silu on s-frags; gate-mult on v-frags (aligned) ----
#pragma unroll
    for (int ct = 0; ct < 2; ++ct)
#pragma unroll
      for (int i = 0; i < 4; ++i) {
        float v = c1[ct][i];
        c1[ct][i] = v * sigmoidf(v);
      }
#pragma unroll
    for (int rt = 1; rt < 4; ++rt)
#pragma unroll
      for (int ct = 0; ct < 2; ++ct)
#pragma unroll
        for (int i = 0; i < 4; ++i)
          c1[rt*2+ct][i] *= (ct == 0 ? g0[i] : g1[i]);

    // ---- transpose t2 (C->A via LDS) ----
#pragma unroll
    for (int rt = 0; rt < 4; ++rt)
#pragma unroll
      for (int ct = 0; ct < 2; ++ct)
#pragma unroll
        for (int i = 0; i < 4; ++i)
          wbuf[(rt*16 + kg*4 + i)*36 + ct*16 + col] = c1[rt*2+ct][i];
    bf16x8 t2A[4];
#pragma unroll
    for (int rt = 0; rt < 4; ++rt) {
      float a8[8];
      *reinterpret_cast<float4*>(&a8[0]) = *reinterpret_cast<const float4*>(&wbuf[(rt*16+col)*36 + kg*8]);
      *reinterpret_cast<float4*>(&a8[4]) = *reinterpret_cast<const float4*>(&wbuf[(rt*16+col)*36 + kg*8 + 4]);
      t2A[rt] = cvt8(a8);
    }

    // ---- lin2 (accumulate onto skip) ----
#pragma unroll
    for (int rt = 0; rt < 4; ++rt)
#pragma unroll
      for (int ct = 0; ct < 2; ++ct)
        co[rt*2+ct] = mfma16(t2A[rt], rt==0 ? Bl2s[ct] : Bl2v[ct], co[rt*2+ct]);
#pragma unroll
    for (int i = 0; i < 8; ++i) co[i] *= INV_C;

    // ---- epilogue: C -> row layout (stride 33), +R, store ----
#pragma unroll
    for (int rt = 0; rt < 4; ++rt)
#pragma unroll
      for (int ct = 0; ct < 2; ++ct)
#pragma unroll
        for (int i = 0; i < 4; ++i)
          wbuf[(rt*16 + kg*4 + i)*33 + ct*16 + col] = co[rt*2+ct][i];

    const int eloc = lane >> 2, comp = lane & 3;
    float o[32];
    {
      const float* rp = &wbuf[(comp*16 + eloc)*33];
#pragma unroll
      for (int m = 0; m < 32; ++m) o[m] = rp[m];
    }
    int e2 = tile*16 + eloc;
    int ec2 = (e2 < E) ? e2 : (E - 1);
    int dn2 = ei[(size_t)E + ec2];
    {
      float r[32];
      ld32h(wsN + (size_t)dn2*512 + 128 + comp*32, r);
#pragma unroll
      for (int c = 0; c < 32; ++c) o[c] += r[c];
    }
    if (comp == 0) {
      if (e2 < E) st32f(offs + (size_t)e2*32, o);
    } else {
#pragma unroll
      for (int c = 0; c < 32; ++c) wbuf[eloc*97 + 3*c + (comp-1)] = o[c];
    }
    // cooperative coalesced offv store (wave-private)
    {
      const size_t obase = (size_t)tile * 1536;
#pragma unroll
      for (int i = 0; i < 6; ++i) {
        int s = i*64 + lane;               // float4 slot in [0,384)
        int row = s / 24, c4 = s - row*24;
        const float* sp = &wbuf[row*97 + c4*4];
        float4 q; q.x = sp[0]; q.y = sp[1]; q.z = sp[2]; q.w = sp[3];
        if (tile*16 + row < E)
          *reinterpret_cast<float4*>(offv + obase + (size_t)s*4) = q;
      }
    }
  }
}

extern "C" void kernel_launch(void* const* d_in, const int* in_sizes, int n_in,
                              void* d_out, int out_size, void* d_ws, size_t ws_size,
                              hipStream_t stream) {
  const float* node_s = (const float*)d_in[0];
  const float* node_v = (const float*)d_in[1];
  const float* tpw    = (const float*)d_in[2];
  const float* resw   = (const float*)d_in[3];
  const int*   ei     = (const int*)d_in[4];
  const int N = in_sizes[0] / 32;
  const int E = in_sizes[4] / 2;

  float* out  = (float*)d_out;
  float* dgs  = out;
  float* dgv  = out + (size_t)N*32;
  float* offs = out + (size_t)N*128;
  float* offv = offs + (size_t)E*32;

  u16* wsB = (u16*)d_ws;               // bf16 scratch: N*512*2 bytes (~51 MB)

  const int nodeGrid = 2 * ((N + 63) / 64);
  const int ntiles = (E + 15) / 16;

  node_kernel<<<nodeGrid, 256, 0, stream>>>(node_s, node_v, tpw, resw,
                                            wsB, dgs, dgv, N);
  int eg = (ntiles + 3) / 4; if (eg > 2048) eg = 2048;
  edge_kernel<<<eg, 256, 0, stream>>>(ei, resw, wsB, offs, offv, E, ntiles);
}

// Round 11
// 338.575 us; speedup vs baseline: 5.5350x; 3.0987x over previous
//
#include <hip/hip_runtime.h>
#include <hip/hip_bf16.h>

#define DEV __device__ __forceinline__

typedef unsigned short u16;
typedef unsigned int u32;

typedef __attribute__((ext_vector_type(8))) short bf16x8;   // 8 bf16 (4 VGPRs)
typedef __attribute__((ext_vector_type(4))) float f32x4;

constexpr float INV_C  = 0.17677669529663687f;   // 1/sqrt(32)
constexpr float INV_S3 = 0.5773502691896258f;    // 1/sqrt(3)

DEV float bf2f(u32 h) { return __uint_as_float(h << 16); }
DEV u32 f2bf_bits(float f) {
  u32 u = __float_as_uint(f);
  u += 0x7fffu + ((u >> 16) & 1u);
  return u >> 16;
}

DEV void st32f(float* __restrict__ p, const float o[32]) {
#pragma unroll
  for (int i = 0; i < 8; ++i) {
    float4 q; q.x=o[4*i+0]; q.y=o[4*i+1]; q.z=o[4*i+2]; q.w=o[4*i+3];
    reinterpret_cast<float4*>(p)[i] = q;
  }
}
DEV void ld32h(const u16* __restrict__ p, float o[32]) {
#pragma unroll
  for (int i = 0; i < 4; ++i) {
    uint4 q = reinterpret_cast<const uint4*>(p)[i];
    u32 w0=q.x, w1=q.y, w2=q.z, w3=q.w;
    o[8*i+0]=bf2f(w0 & 0xffffu); o[8*i+1]=bf2f(w0 >> 16);
    o[8*i+2]=bf2f(w1 & 0xffffu); o[8*i+3]=bf2f(w1 >> 16);
    o[8*i+4]=bf2f(w2 & 0xffffu); o[8*i+5]=bf2f(w2 >> 16);
    o[8*i+6]=bf2f(w3 & 0xffffu); o[8*i+7]=bf2f(w3 >> 16);
  }
}
DEV void st32h(u16* __restrict__ p, const float o[32]) {
#pragma unroll
  for (int i = 0; i < 16; ++i) {
    reinterpret_cast<u32*>(p)[i] = f2bf_bits(o[2*i]) | (f2bf_bits(o[2*i+1]) << 16);
  }
}
// 8-element bf16 slice (16 B, aligned)
DEV void ld8h(const u16* __restrict__ p, float o[8]) {
  uint4 q = *reinterpret_cast<const uint4*>(p);
  o[0]=bf2f(q.x & 0xffffu); o[1]=bf2f(q.x >> 16);
  o[2]=bf2f(q.y & 0xffffu); o[3]=bf2f(q.y >> 16);
  o[4]=bf2f(q.z & 0xffffu); o[5]=bf2f(q.z >> 16);
  o[6]=bf2f(q.w & 0xffffu); o[7]=bf2f(q.w >> 16);
}
DEV bf16x8 cvt8(const float t[8]) {
  bf16x8 r;
#pragma unroll
  for (int j = 0; j < 8; ++j) r[j] = (short)f2bf_bits(t[j]);
  return r;
}

DEV f32x4 mfma16(bf16x8 a, bf16x8 b, f32x4 c) {
  return __builtin_amdgcn_mfma_f32_16x16x32_bf16(a, b, c, 0, 0, 0);
}

// B-fragment for linT orientation: B[k=c][n=d] = W[c*32+d]
DEV bf16x8 ldBfrag(const float* __restrict__ W, int kg, int colbase) {
  bf16x8 r;
#pragma unroll
  for (int j = 0; j < 8; ++j)
    r[j] = (short)f2bf_bits(W[(kg*8 + j)*32 + colbase]);
  return r;
}
// B-fragment for linN orientation: B[k=v][n=u] = W[u*32+v]  (contiguous per lane)
DEV bf16x8 ldBfragT(const float* __restrict__ W, int kg, int colbase) {
  bf16x8 r;
  const float* p = W + colbase*32 + kg*8;
#pragma unroll
  for (int j = 0; j < 8; ++j) r[j] = (short)f2bf_bits(p[j]);
  return r;
}

DEV float sigmoidf(float x) { return 1.f / (1.f + __expf(-x)); }

// ---- MFMA resblock (wave-private). Input A-frags tA (rows s,vx,vy,vz x16),
// weights W7 (7 x 32x32 f32, resblock order), out co = skip + lin2 C-frags.
// wbuf: >= 2304 f32 wave-private LDS. Relies on in-wave in-order LDS ops.
DEV void mfma_resblock(const float* __restrict__ W7, const bf16x8 tA[4],
                       int col, int kg, float* wbuf, f32x4 co[8]) {
  const f32x4 zero4 = {0.f,0.f,0.f,0.f};
  bf16x8 B1s[2], B1v[2], Bg[2], B2s[2], B2v[2], Bks[2], Bkv[2];
#pragma unroll
  for (int ct = 0; ct < 2; ++ct) {
    int cb = ct*16 + col;
    B1s[ct] = ldBfrag(W7 + 0*1024, kg, cb);
    B1v[ct] = ldBfrag(W7 + 1*1024, kg, cb);
    Bg[ct]  = ldBfrag(W7 + 2*1024, kg, cb);
    B2s[ct] = ldBfrag(W7 + 3*1024, kg, cb);
    B2v[ct] = ldBfrag(W7 + 4*1024, kg, cb);
    Bks[ct] = ldBfrag(W7 + 5*1024, kg, cb);
    Bkv[ct] = ldBfrag(W7 + 6*1024, kg, cb);
  }
  f32x4 c1[8];
#pragma unroll
  for (int i = 0; i < 8; ++i) { c1[i] = zero4; co[i] = zero4; }
#pragma unroll
  for (int rt = 0; rt < 4; ++rt)
#pragma unroll
    for (int ct = 0; ct < 2; ++ct) {
      c1[rt*2+ct] = mfma16(tA[rt], rt==0 ? B1s[ct] : B1v[ct], c1[rt*2+ct]);
      co[rt*2+ct] = mfma16(tA[rt], rt==0 ? Bks[ct] : Bkv[ct], co[rt*2+ct]);
    }
#pragma unroll
  for (int i = 0; i < 8; ++i) c1[i] *= INV_C;   // t1

  // gate: transpose t1 s-rows (C->A), MFMA, sigmoid
#pragma unroll
  for (int ct = 0; ct < 2; ++ct)
#pragma unroll
    for (int i = 0; i < 4; ++i)
      wbuf[(kg*4 + i)*36 + ct*16 + col] = c1[ct][i];
  float ag[8];
  *reinterpret_cast<float4*>(&ag[0]) = *reinterpret_cast<const float4*>(&wbuf[col*36 + kg*8]);
  *reinterpret_cast<float4*>(&ag[4]) = *reinterpret_cast<const float4*>(&wbuf[col*36 + kg*8 + 4]);
  bf16x8 Ag = cvt8(ag);
  f32x4 cg0 = mfma16(Ag, Bg[0], zero4);
  f32x4 cg1 = mfma16(Ag, Bg[1], zero4);
  float g0[4], g1[4];
#pragma unroll
  for (int i = 0; i < 4; ++i) {
    g0[i] = sigmoidf(cg0[i]*INV_C);
    g1[i] = sigmoidf(cg1[i]*INV_C);
  }

  // t2: silu on s-frags; gate-mult on v-frags (C layouts aligned)
#pragma unroll
  for (int ct = 0; ct < 2; ++ct)
#pragma unroll
    for (int i = 0; i < 4; ++i) {
      float v = c1[ct][i];
      c1[ct][i] = v * sigmoidf(v);
    }
#pragma unroll
  for (int rt = 1; rt < 4; ++rt)
#pragma unroll
    for (int ct = 0; ct < 2; ++ct)
#pragma unroll
      for (int i = 0; i < 4; ++i)
        c1[rt*2+ct][i] *= (ct == 0 ? g0[i] : g1[i]);

  // transpose t2 (C->A)
#pragma unroll
  for (int rt = 0; rt < 4; ++rt)
#pragma unroll
    for (int ct = 0; ct < 2; ++ct)
#pragma unroll
      for (int i = 0; i < 4; ++i)
        wbuf[(rt*16 + kg*4 + i)*36 + ct*16 + col] = c1[rt*2+ct][i];
  bf16x8 t2A[4];
#pragma unroll
  for (int rt = 0; rt < 4; ++rt) {
    float a8[8];
    *reinterpret_cast<float4*>(&a8[0]) = *reinterpret_cast<const float4*>(&wbuf[(rt*16+col)*36 + kg*8]);
    *reinterpret_cast<float4*>(&a8[4]) = *reinterpret_cast<const float4*>(&wbuf[(rt*16+col)*36 + kg*8 + 4]);
    t2A[rt] = cvt8(a8);
  }

  // lin2 accumulate onto skip
#pragma unroll
  for (int rt = 0; rt < 4; ++rt)
#pragma unroll
    for (int ct = 0; ct < 2; ++ct)
      co[rt*2+ct] = mfma16(t2A[rt], rt==0 ? B2s[ct] : B2v[ct], co[rt*2+ct]);
#pragma unroll
  for (int i = 0; i < 8; ++i) co[i] *= INV_C;
}

// Scratch per node (1024 bf16 = 2 KB):
// A_s@0 A_v@32+32x | R_s@128 R_v@160+32x | B0@256 Vr1@288+32x Vr2@384+32x B3@480
// DS_s@512 DS_v@544+32x | Q_s@640 Q_v@672+32x
// T: sr0@768 vr1@800+32x vr2@896+32x sr3@992

// ============ nodeA: per-wave task = (job, 16-node tile), zero barriers ============
// jobs: 0 res0->A, 1 res2->R, 2 res3->DS, 3 res5->Q, 4 tp1->B rows, 5 tp0->T rows
__global__ __launch_bounds__(256) void nodeA_kernel(
    const float* __restrict__ node_s, const float* __restrict__ node_v,
    const float* __restrict__ tpw, const float* __restrict__ resw,
    u16* __restrict__ wsN, int N, int ntN)
{
  __shared__ __align__(16) float sbuf[9216];
  const int lane = threadIdx.x & 63;
  const int wave = threadIdx.x >> 6;
  float* wbuf = sbuf + wave*2304;
  const int col = lane & 15;
  const int kg  = lane >> 4;

  const int task = blockIdx.x*4 + wave;
  const int job  = task / ntN;
  const int tile = task - job*ntN;
  if (job >= 6) return;

  // feat A-frags (s from node_s; v gathered strided from node_v)
  const int n0 = tile*16 + col;
  const int nc = (n0 < N) ? n0 : (N-1);
  bf16x8 fA[4];
  {
    float t[8];
    const float* ps = node_s + (size_t)nc*32 + kg*8;
#pragma unroll
    for (int j = 0; j < 8; ++j) t[j] = ps[j];
    fA[0] = cvt8(t);
    const float* pv = node_v + (size_t)nc*96 + kg*24;
#pragma unroll
    for (int x = 0; x < 3; ++x) {
      float tv[8];
#pragma unroll
      for (int j = 0; j < 8; ++j) tv[j] = pv[j*3 + x];
      fA[x+1] = cvt8(tv);
    }
  }

  const int eloc = lane >> 2, comp = lane & 3;
  const int n2 = tile*16 + eloc;

  if (job < 4) {
    const int rbi  = (job==0) ? 0 : (job==1) ? 2 : (job==2) ? 3 : 5;
    const int ooff = (job==0) ? 0 : (job==1) ? 128 : (job==2) ? 512 : 640;
    f32x4 co[8];
    mfma_resblock(resw + rbi*7168, fA, col, kg, wbuf, co);
#pragma unroll
    for (int rt = 0; rt < 4; ++rt)
#pragma unroll
      for (int ct = 0; ct < 2; ++ct)
#pragma unroll
        for (int i = 0; i < 4; ++i)
          wbuf[(rt*16 + kg*4 + i)*33 + ct*16 + col] = co[rt*2+ct][i];
    if (n2 < N) {
      float o[32];
      const float* rp = &wbuf[(comp*16 + eloc)*33];
#pragma unroll
      for (int m = 0; m < 32; ++m) o[m] = rp[m];
      st32h(wsN + (size_t)n2*1024 + ooff + comp*32, o);
    }
  } else {
    const float* Wt = (job==4) ? tpw + 4096 : tpw;
    bf16x8 Bw[4][2];
#pragma unroll
    for (int m = 0; m < 4; ++m)
#pragma unroll
      for (int ct = 0; ct < 2; ++ct)
        Bw[m][ct] = ldBfragT(Wt + m*1024, kg, ct*16 + col);
    const int base1  = (job==4) ? 256 : 768;   // pass1: s->B0/sr0, v->Vr1/vr1
    const int base2v = (job==4) ? 384 : 896;   // pass2 v: Vr2/vr2
    const int base2s = (job==4) ? 480 : 992;   // pass2 s: B3/sr3
    const f32x4 zero4 = {0.f,0.f,0.f,0.f};
    // pass1: rt0 x W0, rt1-3 x W1
    {
      f32x4 c[8];
#pragma unroll
      for (int i = 0; i < 8; ++i) c[i] = zero4;
#pragma unroll
      for (int rt = 0; rt < 4; ++rt)
#pragma unroll
        for (int ct = 0; ct < 2; ++ct)
          c[rt*2+ct] = mfma16(fA[rt], rt==0 ? Bw[0][ct] : Bw[1][ct], c[rt*2+ct]);
#pragma unroll
      for (int rt = 0; rt < 4; ++rt)
#pragma unroll
        for (int ct = 0; ct < 2; ++ct)
#pragma unroll
          for (int i = 0; i < 4; ++i)
            wbuf[(rt*16 + kg*4 + i)*33 + ct*16 + col] = c[rt*2+ct][i]*INV_C;
      if (n2 < N) {
        float o[32];
        const float* rp = &wbuf[(comp*16 + eloc)*33];
#pragma unroll
        for (int m = 0; m < 32; ++m) o[m] = rp[m];
        st32h(wsN + (size_t)n2*1024 + base1 + comp*32, o);
      }
    }
    // pass2: rt0 x W3, rt1-3 x W2
    {
      f32x4 c[8];
#pragma unroll
      for (int i = 0; i < 8; ++i) c[i] = zero4;
#pragma unroll
      for (int rt = 0; rt < 4; ++rt)
#pragma unroll
        for (int ct = 0; ct < 2; ++ct)
          c[rt*2+ct] = mfma16(fA[rt], rt==0 ? Bw[3][ct] : Bw[2][ct], c[rt*2+ct]);
#pragma unroll
      for (int rt = 0; rt < 4; ++rt)
#pragma unroll
        for (int ct = 0; ct < 2; ++ct)
#pragma unroll
          for (int i = 0; i < 4; ++i)
            wbuf[(rt*16 + kg*4 + i)*33 + ct*16 + col] = c[rt*2+ct][i]*INV_C;
      if (n2 < N) {
        float o[32];
        const float* rp = &wbuf[(comp*16 + eloc)*33];
#pragma unroll
        for (int m = 0; m < 32; ++m) o[m] = rp[m];
        const int off = (comp==0) ? base2s : base2v + 32*(comp-1);
        st32h(wsN + (size_t)n2*1024 + off, o);
      }
    }
  }
}

// ============ nodeB: TP combine (registers) + res4 + Q-add -> dg ============
__global__ __launch_bounds__(256) void nodeB_kernel(
    const u16* __restrict__ wsN, const float* __restrict__ resw,
    float* __restrict__ dgs, float* __restrict__ dgv, int N, int ntN)
{
  __shared__ __align__(16) float sbuf[9216];
  const int lane = threadIdx.x & 63;
  const int wave = threadIdx.x >> 6;
  float* wbuf = sbuf + wave*2304;
  const int col = lane & 15;
  const int kg  = lane >> 4;

  const int tile = blockIdx.x*4 + wave;
  if (tile >= ntN) return;

  const int n0 = tile*16 + col;
  const int nc = (n0 < N) ? n0 : (N-1);
  const u16* P = wsN + (size_t)nc*1024 + kg*8;

  // TP combine in A-row space (all elementwise per lane)
  float DSs[8], DSv0[8], DSv1[8], DSv2[8], b[8], acc[8], t[8];
  ld8h(P + 512, DSs);
  ld8h(P + 544, DSv0);
  ld8h(P + 576, DSv1);
  ld8h(P + 608, DSv2);

  bf16x8 tA[4];
  ld8h(P + 768, b);                               // sr0
#pragma unroll
  for (int j = 0; j < 8; ++j) t[j] = DSs[j]*b[j];
  ld8h(P + 800, b);                               // vr1_x
#pragma unroll
  for (int j = 0; j < 8; ++j) acc[j] = DSv0[j]*b[j];
  ld8h(P + 832, b);
#pragma unroll
  for (int j = 0; j < 8; ++j) acc[j] = __builtin_fmaf(DSv1[j], b[j], acc[j]);
  ld8h(P + 864, b);
#pragma unroll
  for (int j = 0; j < 8; ++j) acc[j] = __builtin_fmaf(DSv2[j], b[j], acc[j]);
#pragma unroll
  for (int j = 0; j < 8; ++j) t[j] = __builtin_fmaf(acc[j], INV_S3, t[j]);
  tA[0] = cvt8(t);

  float sr3[8];
  ld8h(P + 992, sr3);
  ld8h(P + 896, b);
#pragma unroll
  for (int j = 0; j < 8; ++j) t[j] = DSs[j]*b[j] + DSv0[j]*sr3[j];
  tA[1] = cvt8(t);
  ld8h(P + 928, b);
#pragma unroll
  for (int j = 0; j < 8; ++j) t[j] = DSs[j]*b[j] + DSv1[j]*sr3[j];
  tA[2] = cvt8(t);
  ld8h(P + 960, b);
#pragma unroll
  for (int j = 0; j < 8; ++j) t[j] = DSs[j]*b[j] + DSv2[j]*sr3[j];
  tA[3] = cvt8(t);

  // res4
  f32x4 co[8];
  mfma_resblock(resw + 4*7168, tA, col, kg, wbuf, co);

  // epilogue: C->rows, +Q, store dgs/dgv
#pragma unroll
  for (int rt = 0; rt < 4; ++rt)
#pragma unroll
    for (int ct = 0; ct < 2; ++ct)
#pragma unroll
      for (int i = 0; i < 4; ++i)
        wbuf[(rt*16 + kg*4 + i)*33 + ct*16 + col] = co[rt*2+ct][i];

  const int eloc = lane >> 2, comp = lane & 3;
  const int n2 = tile*16 + eloc;
  const int nc2 = (n2 < N) ? n2 : (N-1);
  float o[32];
  {
    const float* rp = &wbuf[(comp*16 + eloc)*33];
#pragma unroll
    for (int m = 0; m < 32; ++m) o[m] = rp[m];
  }
  {
    float q[32];
    ld32h(wsN + (size_t)nc2*1024 + 640 + comp*32, q);
#pragma unroll
    for (int c = 0; c < 32; ++c) o[c] += q[c];
  }
  if (comp == 0) {
    if (n2 < N) st32f(dgs + (size_t)n2*32, o);
  } else {
#pragma unroll
    for (int c = 0; c < 32; ++c) wbuf[eloc*97 + 3*c + (comp-1)] = o[c];
  }
  {
    const size_t obase = (size_t)tile * 1536;
#pragma unroll
    for (int i = 0; i < 6; ++i) {
      int s = i*64 + lane;
      int row = s / 24, c4 = s - row*24;
      const float* sp = &wbuf[row*97 + c4*4];
      float4 q; q.x = sp[0]; q.y = sp[1]; q.z = sp[2]; q.w = sp[3];
      if (tile*16 + row < N)
        *reinterpret_cast<float4*>(dgv + obase + (size_t)s*4) = q;
    }
  }
}

// ============ edge kernel (round-10 validated; scratch stride 512 -> 1024) ============
__global__ __launch_bounds__(256) void edge_kernel(
    const int* __restrict__ ei, const float* __restrict__ resw,
    const u16* __restrict__ wsN,
    float* __restrict__ offs, float* __restrict__ offv, int E, int ntiles)
{
  __shared__ __align__(16) float sbuf[9216];
  const int lane = threadIdx.x & 63;
  const int wave = threadIdx.x >> 6;
  float* wbuf = sbuf + wave*2304;

  const int col = lane & 15;
  const int kg  = lane >> 4;

  const float* W = resw + 7168;
  bf16x8 Bs1[2], Bv1[2], Bg[2], Bl2s[2], Bl2v[2], Bsks[2], Bskv[2];
#pragma unroll
  for (int ct = 0; ct < 2; ++ct) {
    int cb = ct*16 + col;
    Bs1[ct]  = ldBfrag(W + 0*1024, kg, cb);
    Bv1[ct]  = ldBfrag(W + 1*1024, kg, cb);
    Bg[ct]   = ldBfrag(W + 2*1024, kg, cb);
    Bl2s[ct] = ldBfrag(W + 3*1024, kg, cb);
    Bl2v[ct] = ldBfrag(W + 4*1024, kg, cb);
    Bsks[ct] = ldBfrag(W + 5*1024, kg, cb);
    Bskv[ct] = ldBfrag(W + 6*1024, kg, cb);
  }

  const int wid = blockIdx.x*4 + wave;
  const int wstride = gridDim.x*4;
  const f32x4 zero4 = {0.f, 0.f, 0.f, 0.f};

  for (int tile = wid; tile < ntiles; tile += wstride) {
    int e = tile*16 + col;
    int ec = (e < E) ? e : (E - 1);
    int sn = ei[ec], dn = ei[(size_t)E + ec];
    const u16* S = wsN + (size_t)sn*1024 + kg*8;
    const u16* D = wsN + (size_t)dn*1024 + kg*8;

    float As[8], Av0[8], Av1[8], Av2[8], b[8], acc[8], t[8];
    ld8h(D + 0,  As);
    ld8h(D + 32, Av0);
    ld8h(D + 64, Av1);
    ld8h(D + 96, Av2);

    bf16x8 tA[4];
    ld8h(S + 256, b);
#pragma unroll
    for (int j = 0; j < 8; ++j) t[j] = As[j]*b[j];
    ld8h(S + 288, b);
#pragma unroll
    for (int j = 0; j < 8; ++j) acc[j] = Av0[j]*b[j];
    ld8h(S + 320, b);
#pragma unroll
    for (int j = 0; j < 8; ++j) acc[j] = __builtin_fmaf(Av1[j], b[j], acc[j]);
    ld8h(S + 352, b);
#pragma unroll
    for (int j = 0; j < 8; ++j) acc[j] = __builtin_fmaf(Av2[j], b[j], acc[j]);
#pragma unroll
    for (int j = 0; j < 8; ++j) t[j] = __builtin_fmaf(acc[j], INV_S3, t[j]);
    tA[0] = cvt8(t);

    ld8h(S + 480, acc);                         // B3
    ld8h(S + 384, b);
#pragma unroll
    for (int j = 0; j < 8; ++j) t[j] = As[j]*b[j] + Av0[j]*acc[j];
    tA[1] = cvt8(t);
    ld8h(S + 416, b);
#pragma unroll
    for (int j = 0; j < 8; ++j) t[j] = As[j]*b[j] + Av1[j]*acc[j];
    tA[2] = cvt8(t);
    ld8h(S + 448, b);
#pragma unroll
    for (int j = 0; j < 8; ++j) t[j] = As[j]*b[j] + Av2[j]*acc[j];
    tA[3] = cvt8(t);

    f32x4 c1[8], co[8];
#pragma unroll
    for (int i = 0; i < 8; ++i) { c1[i] = zero4; co[i] = zero4; }
#pragma unroll
    for (int rt = 0; rt < 4; ++rt) {
#pragma unroll
      for (int ct = 0; ct < 2; ++ct) {
        c1[rt*2+ct] = mfma16(tA[rt], rt==0 ? Bs1[ct] : Bv1[ct], c1[rt*2+ct]);
        co[rt*2+ct] = mfma16(tA[rt], rt==0 ? Bsks[ct] : Bskv[ct], co[rt*2+ct]);
      }
    }
#pragma unroll
    for (int i = 0; i < 8; ++i) c1[i] *= INV_C;

#pragma unroll
    for (int ct = 0; ct < 2; ++ct)
#pragma unroll
      for (int i = 0; i < 4; ++i)
        wbuf[(kg*4 + i)*36 + ct*16 + col] = c1[ct][i];
    float ag[8];
    *reinterpret_cast<float4*>(&ag[0]) = *reinterpret_cast<const float4*>(&wbuf[col*36 + kg*8]);
    *reinterpret_cast<float4*>(&ag[4]) = *reinterpret_cast<const float4*>(&wbuf[col*36 + kg*8 + 4]);
    bf16x8 Ag = cvt8(ag);
    f32x4 cg0 = mfma16(Ag, Bg[0], zero4);
    f32x4 cg1 = mfma16(Ag, Bg[1], zero4);
    float g0[4], g1[4];
#pragma unroll
    for (int i = 0; i < 4; ++i) {
      g0[i] = sigmoidf(cg0[i]*INV_C);
      g1[i] = sigmoidf(cg1[i]*INV_C);
    }

#pragma unroll
    for (int ct = 0; ct < 2; ++ct)
#pragma unroll
      for (int i = 0; i < 4; ++i) {
        float v = c1[ct][i];
        c1[ct][i] = v * sigmoidf(v);
      }
#pragma unroll
    for (int rt = 1; rt < 4; ++rt)
#pragma unroll
      for (int ct = 0; ct < 2; ++ct)
#pragma unroll
        for (int i = 0; i < 4; ++i)
          c1[rt*2+ct][i] *= (ct == 0 ? g0[i] : g1[i]);

#pragma unroll
    for (int rt = 0; rt < 4; ++rt)
#pragma unroll
      for (int ct = 0; ct < 2; ++ct)
#pragma unroll
        for (int i = 0; i < 4; ++i)
          wbuf[(rt*16 + kg*4 + i)*36 + ct*16 + col] = c1[rt*2+ct][i];
    bf16x8 t2A[4];
#pragma unroll
    for (int rt = 0; rt < 4; ++rt) {
      float a8[8];
      *reinterpret_cast<float4*>(&a8[0]) = *reinterpret_cast<const float4*>(&wbuf[(rt*16+col)*36 + kg*8]);
      *reinterpret_cast<float4*>(&a8[4]) = *reinterpret_cast<const float4*>(&wbuf[(rt*16+col)*36 + kg*8 + 4]);
      t2A[rt] = cvt8(a8);
    }

#pragma unroll
    for (int rt = 0; rt < 4; ++rt)
#pragma unroll
      for (int ct = 0; ct < 2; ++ct)
        co[rt*2+ct] = mfma16(t2A[rt], rt==0 ? Bl2s[ct] : Bl2v[ct], co[rt*2+ct]);
#pragma unroll
    for (int i = 0; i < 8; ++i) co[i] *= INV_C;

#pragma unroll
    for (int rt = 0; rt < 4; ++rt)
#pragma unroll
      for (int ct = 0; ct < 2; ++ct)
#pragma unroll
        for (int i = 0; i < 4; ++i)
          wbuf[(rt*16 + kg*4 + i)*33 + ct*16 + col] = co[rt*2+ct][i];

    const int eloc = lane >> 2, comp = lane & 3;
    float o[32];
    {
      const float* rp = &wbuf[(comp*16 + eloc)*33];
#pragma unroll
      for (int m = 0; m < 32; ++m) o[m] = rp[m];
    }
    int e2 = tile*16 + eloc;
    int ec2 = (e2 < E) ? e2 : (E - 1);
    int dn2 = ei[(size_t)E + ec2];
    {
      float r[32];
      ld32h(wsN + (size_t)dn2*1024 + 128 + comp*32, r);
#pragma unroll
      for (int c = 0; c < 32; ++c) o[c] += r[c];
    }
    if (comp == 0) {
      if (e2 < E) st32f(offs + (size_t)e2*32, o);
    } else {
#pragma unroll
      for (int c = 0; c < 32; ++c) wbuf[eloc*97 + 3*c + (comp-1)] = o[c];
    }
    {
      const size_t obase = (size_t)tile * 1536;
#pragma unroll
      for (int i = 0; i < 6; ++i) {
        int s = i*64 + lane;
        int row = s / 24, c4 = s - row*24;
        const float* sp = &wbuf[row*97 + c4*4];
        float4 q; q.x = sp[0]; q.y = sp[1]; q.z = sp[2]; q.w = sp[3];
        if (tile*16 + row < E)
          *reinterpret_cast<float4*>(offv + obase + (size_t)s*4) = q;
      }
    }
  }
}

extern "C" void kernel_launch(void* const* d_in, const int* in_sizes, int n_in,
                              void* d_out, int out_size, void* d_ws, size_t ws_size,
                              hipStream_t stream) {
  const float* node_s = (const float*)d_in[0];
  const float* node_v = (const float*)d_in[1];
  const float* tpw    = (const float*)d_in[2];
  const float* resw   = (const float*)d_in[3];
  const int*   ei     = (const int*)d_in[4];
  const int N = in_sizes[0] / 32;
  const int E = in_sizes[4] / 2;

  float* out  = (float*)d_out;
  float* dgs  = out;
  float* dgv  = out + (size_t)N*32;
  float* offs = out + (size_t)N*128;
  float* offv = offs + (size_t)E*32;

  u16* wsB = (u16*)d_ws;               // bf16 scratch: N*1024*2 B (~102 MB)

  const int ntN = (N + 15) / 16;
  const int ntE = (E + 15) / 16;

  const int aBlocks = (6*ntN + 3) / 4;
  const int bBlocks = (ntN + 3) / 4;
  int eg = (ntE + 3) / 4; if (eg > 2048) eg = 2048;

  nodeA_kernel<<<aBlocks, 256, 0, stream>>>(node_s, node_v, tpw, resw, wsB, N, ntN);
  nodeB_kernel<<<bBlocks, 256, 0, stream>>>(wsB, resw, dgs, dgv, N, ntN);
  edge_kernel<<<eg, 256, 0, stream>>>(ei, resw, wsB, offs, offv, E, ntE);
}

// Round 12
// 302.053 us; speedup vs baseline: 6.2042x; 1.1209x over previous
//
#include <hip/hip_runtime.h>
#include <hip/hip_bf16.h>

#define DEV __device__ __forceinline__

typedef unsigned short u16;
typedef unsigned int u32;

typedef __attribute__((ext_vector_type(8))) short bf16x8;   // 8 bf16 (4 VGPRs)
typedef __attribute__((ext_vector_type(4))) float f32x4;

constexpr float INV_C  = 0.17677669529663687f;   // 1/sqrt(32)
constexpr float INV_S3 = 0.5773502691896258f;    // 1/sqrt(3)

DEV float bf2f(u32 h) { return __uint_as_float(h << 16); }
DEV u32 f2bf_bits(float f) {
  u32 u = __float_as_uint(f);
  u += 0x7fffu + ((u >> 16) & 1u);
  return u >> 16;
}

DEV void st32f(float* __restrict__ p, const float o[32]) {
#pragma unroll
  for (int i = 0; i < 8; ++i) {
    float4 q; q.x=o[4*i+0]; q.y=o[4*i+1]; q.z=o[4*i+2]; q.w=o[4*i+3];
    reinterpret_cast<float4*>(p)[i] = q;
  }
}
DEV void ld32h(const u16* __restrict__ p, float o[32]) {
#pragma unroll
  for (int i = 0; i < 4; ++i) {
    uint4 q = reinterpret_cast<const uint4*>(p)[i];
    u32 w0=q.x, w1=q.y, w2=q.z, w3=q.w;
    o[8*i+0]=bf2f(w0 & 0xffffu); o[8*i+1]=bf2f(w0 >> 16);
    o[8*i+2]=bf2f(w1 & 0xffffu); o[8*i+3]=bf2f(w1 >> 16);
    o[8*i+4]=bf2f(w2 & 0xffffu); o[8*i+5]=bf2f(w2 >> 16);
    o[8*i+6]=bf2f(w3 & 0xffffu); o[8*i+7]=bf2f(w3 >> 16);
  }
}
DEV void st32h(u16* __restrict__ p, const float o[32]) {
#pragma unroll
  for (int i = 0; i < 16; ++i) {
    reinterpret_cast<u32*>(p)[i] = f2bf_bits(o[2*i]) | (f2bf_bits(o[2*i+1]) << 16);
  }
}
// unpack 8 bf16 from a raw uint4
DEV void cv8(uint4 q, float o[8]) {
  o[0]=bf2f(q.x & 0xffffu); o[1]=bf2f(q.x >> 16);
  o[2]=bf2f(q.y & 0xffffu); o[3]=bf2f(q.y >> 16);
  o[4]=bf2f(q.z & 0xffffu); o[5]=bf2f(q.z >> 16);
  o[6]=bf2f(q.w & 0xffffu); o[7]=bf2f(q.w >> 16);
}
// 8-element bf16 slice (16 B, aligned)
DEV void ld8h(const u16* __restrict__ p, float o[8]) {
  cv8(*reinterpret_cast<const uint4*>(p), o);
}
DEV bf16x8 cvt8(const float t[8]) {
  bf16x8 r;
#pragma unroll
  for (int j = 0; j < 8; ++j) r[j] = (short)f2bf_bits(t[j]);
  return r;
}

DEV f32x4 mfma16(bf16x8 a, bf16x8 b, f32x4 c) {
  return __builtin_amdgcn_mfma_f32_16x16x32_bf16(a, b, c, 0, 0, 0);
}

// B-fragment, linT orientation, PRE-SCALED by INV_C: B[k=c][n=d] = W[c*32+d]*INV_C
DEV bf16x8 ldBfrag(const float* __restrict__ W, int kg, int colbase) {
  bf16x8 r;
#pragma unroll
  for (int j = 0; j < 8; ++j)
    r[j] = (short)f2bf_bits(W[(kg*8 + j)*32 + colbase] * INV_C);
  return r;
}
// B-fragment, linN orientation, PRE-SCALED: B[k=v][n=u] = W[u*32+v]*INV_C
DEV bf16x8 ldBfragT(const float* __restrict__ W, int kg, int colbase) {
  bf16x8 r;
  const float* p = W + colbase*32 + kg*8;
#pragma unroll
  for (int j = 0; j < 8; ++j) r[j] = (short)f2bf_bits(p[j] * INV_C);
  return r;
}

DEV float sigmoidf(float x) { return 1.f / (1.f + __expf(-x)); }

// ---- MFMA resblock (wave-private, weights pre-scaled by INV_C at frag load).
// tA: A-frags rows (s,vx,vy,vz)x16; co out = skip + lin2 C-frags.
DEV void mfma_resblock(const float* __restrict__ W7, const bf16x8 tA[4],
                       int col, int kg, float* wbuf, f32x4 co[8]) {
  const f32x4 zero4 = {0.f,0.f,0.f,0.f};
  bf16x8 B1s[2], B1v[2], Bg[2], B2s[2], B2v[2], Bks[2], Bkv[2];
#pragma unroll
  for (int ct = 0; ct < 2; ++ct) {
    int cb = ct*16 + col;
    B1s[ct] = ldBfrag(W7 + 0*1024, kg, cb);
    B1v[ct] = ldBfrag(W7 + 1*1024, kg, cb);
    Bg[ct]  = ldBfrag(W7 + 2*1024, kg, cb);
    B2s[ct] = ldBfrag(W7 + 3*1024, kg, cb);
    B2v[ct] = ldBfrag(W7 + 4*1024, kg, cb);
    Bks[ct] = ldBfrag(W7 + 5*1024, kg, cb);
    Bkv[ct] = ldBfrag(W7 + 6*1024, kg, cb);
  }
  f32x4 c1[8];
#pragma unroll
  for (int i = 0; i < 8; ++i) { c1[i] = zero4; co[i] = zero4; }
#pragma unroll
  for (int rt = 0; rt < 4; ++rt)
#pragma unroll
    for (int ct = 0; ct < 2; ++ct) {
      c1[rt*2+ct] = mfma16(tA[rt], rt==0 ? B1s[ct] : B1v[ct], c1[rt*2+ct]);
      co[rt*2+ct] = mfma16(tA[rt], rt==0 ? Bks[ct] : Bkv[ct], co[rt*2+ct]);
    }
  // c1 is t1 (scale folded into B)

  // gate: transpose t1 s-rows (C->A), MFMA, sigmoid
#pragma unroll
  for (int ct = 0; ct < 2; ++ct)
#pragma unroll
    for (int i = 0; i < 4; ++i)
      wbuf[(kg*4 + i)*36 + ct*16 + col] = c1[ct][i];
  float ag[8];
  *reinterpret_cast<float4*>(&ag[0]) = *reinterpret_cast<const float4*>(&wbuf[col*36 + kg*8]);
  *reinterpret_cast<float4*>(&ag[4]) = *reinterpret_cast<const float4*>(&wbuf[col*36 + kg*8 + 4]);
  bf16x8 Ag = cvt8(ag);
  f32x4 cg0 = mfma16(Ag, Bg[0], zero4);
  f32x4 cg1 = mfma16(Ag, Bg[1], zero4);
  float g0[4], g1[4];
#pragma unroll
  for (int i = 0; i < 4; ++i) {
    g0[i] = sigmoidf(cg0[i]);
    g1[i] = sigmoidf(cg1[i]);
  }

  // t2: silu on s-frags; gate-mult on v-frags (C layouts aligned)
#pragma unroll
  for (int ct = 0; ct < 2; ++ct)
#pragma unroll
    for (int i = 0; i < 4; ++i) {
      float v = c1[ct][i];
      c1[ct][i] = v * sigmoidf(v);
    }
#pragma unroll
  for (int rt = 1; rt < 4; ++rt)
#pragma unroll
    for (int ct = 0; ct < 2; ++ct)
#pragma unroll
      for (int i = 0; i < 4; ++i)
        c1[rt*2+ct][i] *= (ct == 0 ? g0[i] : g1[i]);

  // transpose t2 (C->A)
#pragma unroll
  for (int rt = 0; rt < 4; ++rt)
#pragma unroll
    for (int ct = 0; ct < 2; ++ct)
#pragma unroll
      for (int i = 0; i < 4; ++i)
        wbuf[(rt*16 + kg*4 + i)*36 + ct*16 + col] = c1[rt*2+ct][i];
  bf16x8 t2A[4];
#pragma unroll
  for (int rt = 0; rt < 4; ++rt) {
    float a8[8];
    *reinterpret_cast<float4*>(&a8[0]) = *reinterpret_cast<const float4*>(&wbuf[(rt*16+col)*36 + kg*8]);
    *reinterpret_cast<float4*>(&a8[4]) = *reinterpret_cast<const float4*>(&wbuf[(rt*16+col)*36 + kg*8 + 4]);
    t2A[rt] = cvt8(a8);
  }

  // lin2 accumulate onto skip (scale folded)
#pragma unroll
  for (int rt = 0; rt < 4; ++rt)
#pragma unroll
    for (int ct = 0; ct < 2; ++ct)
      co[rt*2+ct] = mfma16(t2A[rt], rt==0 ? B2s[ct] : B2v[ct], co[rt*2+ct]);
}

// Scratch (bf16), SPLIT:
// wsE per node (512): A_s@0 A_v@32+32x | R_s@128 R_v@160+32x | B0@256 Vr1@288+32x Vr2@384+32x B3@480
// wsD per node (512): DS_s@0 DS_v@32+32x | Q_s@128 Q_v@160+32x | sr0@256 vr1@288+32x vr2@384+32x sr3@480

// ============ nodeA: per-wave task = (job, 16-node tile), zero barriers ============
// jobs: 0 res0->E.A, 1 res2->E.R, 2 res3->D.DS, 3 res5->D.Q, 4 tp1->E.B, 5 tp0->D.T
__global__ __launch_bounds__(256) void nodeA_kernel(
    const float* __restrict__ node_s, const float* __restrict__ node_v,
    const float* __restrict__ tpw, const float* __restrict__ resw,
    u16* __restrict__ wsE, u16* __restrict__ wsD, int N, int ntN)
{
  __shared__ __align__(16) float sbuf[9216];
  const int lane = threadIdx.x & 63;
  const int wave = threadIdx.x >> 6;
  float* wbuf = sbuf + wave*2304;
  const int col = lane & 15;
  const int kg  = lane >> 4;

  const int task = blockIdx.x*4 + wave;
  const int job  = task / ntN;
  const int tile = task - job*ntN;
  if (job >= 6) return;

  const int n0 = tile*16 + col;
  const int nc = (n0 < N) ? n0 : (N-1);
  bf16x8 fA[4];
  {
    float t[8];
    const float* ps = node_s + (size_t)nc*32 + kg*8;
#pragma unroll
    for (int j = 0; j < 8; ++j) t[j] = ps[j];
    fA[0] = cvt8(t);
    const float* pv = node_v + (size_t)nc*96 + kg*24;
#pragma unroll
    for (int x = 0; x < 3; ++x) {
      float tv[8];
#pragma unroll
      for (int j = 0; j < 8; ++j) tv[j] = pv[j*3 + x];
      fA[x+1] = cvt8(tv);
    }
  }

  const int eloc = lane >> 2, comp = lane & 3;
  const int n2 = tile*16 + eloc;

  if (job < 4) {
    const int rbi  = (job==0) ? 0 : (job==1) ? 2 : (job==2) ? 3 : 5;
    u16* bp = (job < 2) ? wsE : wsD;
    const int ooff = ((job & 1) == 0) ? 0 : 128;
    f32x4 co[8];
    mfma_resblock(resw + rbi*7168, fA, col, kg, wbuf, co);
#pragma unroll
    for (int rt = 0; rt < 4; ++rt)
#pragma unroll
      for (int ct = 0; ct < 2; ++ct)
#pragma unroll
        for (int i = 0; i < 4; ++i)
          wbuf[(rt*16 + kg*4 + i)*33 + ct*16 + col] = co[rt*2+ct][i];
    if (n2 < N) {
      float o[32];
      const float* rp = &wbuf[(comp*16 + eloc)*33];
#pragma unroll
      for (int m = 0; m < 32; ++m) o[m] = rp[m];
      st32h(bp + (size_t)n2*512 + ooff + comp*32, o);
    }
  } else {
    const float* Wt = (job==4) ? tpw + 4096 : tpw;
    u16* bp = (job==4) ? wsE : wsD;
    bf16x8 Bw[4][2];
#pragma unroll
    for (int m = 0; m < 4; ++m)
#pragma unroll
      for (int ct = 0; ct < 2; ++ct)
        Bw[m][ct] = ldBfragT(Wt + m*1024, kg, ct*16 + col);
    const f32x4 zero4 = {0.f,0.f,0.f,0.f};
    // pass1: rt0 x W0 (->@256), rt1-3 x W1 (->@288+32x)
    {
      f32x4 c[8];
#pragma unroll
      for (int i = 0; i < 8; ++i) c[i] = zero4;
#pragma unroll
      for (int rt = 0; rt < 4; ++rt)
#pragma unroll
        for (int ct = 0; ct < 2; ++ct)
          c[rt*2+ct] = mfma16(fA[rt], rt==0 ? Bw[0][ct] : Bw[1][ct], c[rt*2+ct]);
#pragma unroll
      for (int rt = 0; rt < 4; ++rt)
#pragma unroll
        for (int ct = 0; ct < 2; ++ct)
#pragma unroll
          for (int i = 0; i < 4; ++i)
            wbuf[(rt*16 + kg*4 + i)*33 + ct*16 + col] = c[rt*2+ct][i];
      if (n2 < N) {
        float o[32];
        const float* rp = &wbuf[(comp*16 + eloc)*33];
#pragma unroll
        for (int m = 0; m < 32; ++m) o[m] = rp[m];
        st32h(bp + (size_t)n2*512 + 256 + comp*32, o);
      }
    }
    // pass2: rt0 x W3 (->@480), rt1-3 x W2 (->@384+32x)
    {
      f32x4 c[8];
#pragma unroll
      for (int i = 0; i < 8; ++i) c[i] = zero4;
#pragma unroll
      for (int rt = 0; rt < 4; ++rt)
#pragma unroll
        for (int ct = 0; ct < 2; ++ct)
          c[rt*2+ct] = mfma16(fA[rt], rt==0 ? Bw[3][ct] : Bw[2][ct], c[rt*2+ct]);
#pragma unroll
      for (int rt = 0; rt < 4; ++rt)
#pragma unroll
        for (int ct = 0; ct < 2; ++ct)
#pragma unroll
          for (int i = 0; i < 4; ++i)
            wbuf[(rt*16 + kg*4 + i)*33 + ct*16 + col] = c[rt*2+ct][i];
      if (n2 < N) {
        float o[32];
        const float* rp = &wbuf[(comp*16 + eloc)*33];
#pragma unroll
        for (int m = 0; m < 32; ++m) o[m] = rp[m];
        const int off = (comp==0) ? 480 : 384 + 32*(comp-1);
        st32h(bp + (size_t)n2*512 + off, o);
      }
    }
  }
}

// ============ merged kernel: edge tiles (blocks < egB) + nodeB tiles ============
__global__ __launch_bounds__(256) void edgeB_kernel(
    const int* __restrict__ ei, const float* __restrict__ resw,
    const u16* __restrict__ wsE, const u16* __restrict__ wsD,
    float* __restrict__ offs, float* __restrict__ offv,
    float* __restrict__ dgs, float* __restrict__ dgv,
    int E, int ntE, int N, int ntN, int egB)
{
  __shared__ __align__(16) float sbuf[9216];
  const int lane = threadIdx.x & 63;
  const int wave = threadIdx.x >> 6;
  float* wbuf = sbuf + wave*2304;
  const int col = lane & 15;
  const int kg  = lane >> 4;
  const f32x4 zero4 = {0.f, 0.f, 0.f, 0.f};

  if ((int)blockIdx.x >= egB) {
    // -------- nodeB path: TP combine + res4 + Q -> dg --------
    const int tile = ((int)blockIdx.x - egB)*4 + wave;
    if (tile >= ntN) return;
    const int n0 = tile*16 + col;
    const int nc = (n0 < N) ? n0 : (N-1);
    const u16* P = wsD + (size_t)nc*512 + kg*8;

    float DSs[8], DSv0[8], DSv1[8], DSv2[8], b[8], acc[8], t[8];
    ld8h(P + 0,  DSs);
    ld8h(P + 32, DSv0);
    ld8h(P + 64, DSv1);
    ld8h(P + 96, DSv2);

    bf16x8 tA[4];
    ld8h(P + 256, b);                               // sr0
#pragma unroll
    for (int j = 0; j < 8; ++j) t[j] = DSs[j]*b[j];
    ld8h(P + 288, b);                               // vr1_x
#pragma unroll
    for (int j = 0; j < 8; ++j) acc[j] = DSv0[j]*b[j];
    ld8h(P + 320, b);
#pragma unroll
    for (int j = 0; j < 8; ++j) acc[j] = __builtin_fmaf(DSv1[j], b[j], acc[j]);
    ld8h(P + 352, b);
#pragma unroll
    for (int j = 0; j < 8; ++j) acc[j] = __builtin_fmaf(DSv2[j], b[j], acc[j]);
#pragma unroll
    for (int j = 0; j < 8; ++j) t[j] = __builtin_fmaf(acc[j], INV_S3, t[j]);
    tA[0] = cvt8(t);

    float sr3[8];
    ld8h(P + 480, sr3);
    ld8h(P + 384, b);
#pragma unroll
    for (int j = 0; j < 8; ++j) t[j] = DSs[j]*b[j] + DSv0[j]*sr3[j];
    tA[1] = cvt8(t);
    ld8h(P + 416, b);
#pragma unroll
    for (int j = 0; j < 8; ++j) t[j] = DSs[j]*b[j] + DSv1[j]*sr3[j];
    tA[2] = cvt8(t);
    ld8h(P + 448, b);
#pragma unroll
    for (int j = 0; j < 8; ++j) t[j] = DSs[j]*b[j] + DSv2[j]*sr3[j];
    tA[3] = cvt8(t);

    f32x4 co[8];
    mfma_resblock(resw + 4*7168, tA, col, kg, wbuf, co);

#pragma unroll
    for (int rt = 0; rt < 4; ++rt)
#pragma unroll
      for (int ct = 0; ct < 2; ++ct)
#pragma unroll
        for (int i = 0; i < 4; ++i)
          wbuf[(rt*16 + kg*4 + i)*33 + ct*16 + col] = co[rt*2+ct][i];

    const int eloc = lane >> 2, comp = lane & 3;
    const int n2 = tile*16 + eloc;
    const int nc2 = (n2 < N) ? n2 : (N-1);
    float o[32];
    {
      const float* rp = &wbuf[(comp*16 + eloc)*33];
#pragma unroll
      for (int m = 0; m < 32; ++m) o[m] = rp[m];
    }
    {
      float q[32];
      ld32h(wsD + (size_t)nc2*512 + 128 + comp*32, q);
#pragma unroll
      for (int c = 0; c < 32; ++c) o[c] += q[c];
    }
    if (comp == 0) {
      if (n2 < N) st32f(dgs + (size_t)n2*32, o);
    } else {
#pragma unroll
      for (int c = 0; c < 32; ++c) wbuf[eloc*97 + 3*c + (comp-1)] = o[c];
    }
    {
      const size_t obase = (size_t)tile * 1536;
#pragma unroll
      for (int i = 0; i < 6; ++i) {
        int s = i*64 + lane;
        int row = s / 24, c4 = s - row*24;
        const float* sp = &wbuf[row*97 + c4*4];
        float4 q; q.x = sp[0]; q.y = sp[1]; q.z = sp[2]; q.w = sp[3];
        if (tile*16 + row < N)
          *reinterpret_cast<float4*>(dgv + obase + (size_t)s*4) = q;
      }
    }
    return;
  }

  // -------- edge path --------
  const float* W = resw + 7168;
  bf16x8 Bs1[2], Bv1[2], Bg[2], Bl2s[2], Bl2v[2], Bsks[2], Bskv[2];
#pragma unroll
  for (int ct = 0; ct < 2; ++ct) {
    int cb = ct*16 + col;
    Bs1[ct]  = ldBfrag(W + 0*1024, kg, cb);
    Bv1[ct]  = ldBfrag(W + 1*1024, kg, cb);
    Bg[ct]   = ldBfrag(W + 2*1024, kg, cb);
    Bl2s[ct] = ldBfrag(W + 3*1024, kg, cb);
    Bl2v[ct] = ldBfrag(W + 4*1024, kg, cb);
    Bsks[ct] = ldBfrag(W + 5*1024, kg, cb);
    Bskv[ct] = ldBfrag(W + 6*1024, kg, cb);
  }

  const int wstride = egB*4;
  int tile = blockIdx.x*4 + wave;
  if (tile >= ntE) return;

  // prefetch first tile: indices + dst A-rows (raw)
  int sn_n, dn_n;
  uint4 dA0, dA1, dA2, dA3;
  {
    int e = tile*16 + col;
    int ec = (e < E) ? e : (E-1);
    sn_n = ei[ec]; dn_n = ei[(size_t)E + ec];
    const u16* Dp = wsE + (size_t)dn_n*512 + kg*8;
    dA0 = *reinterpret_cast<const uint4*>(Dp +  0);
    dA1 = *reinterpret_cast<const uint4*>(Dp + 32);
    dA2 = *reinterpret_cast<const uint4*>(Dp + 64);
    dA3 = *reinterpret_cast<const uint4*>(Dp + 96);
  }

  for (;;) {
    const int ctile = tile;
    const int sn = sn_n;
    uint4 cA0 = dA0, cA1 = dA1, cA2 = dA2, cA3 = dA3;

    tile += wstride;
    if (tile < ntE) {              // issue next-tile prefetch
      int e = tile*16 + col;
      int ec = (e < E) ? e : (E-1);
      sn_n = ei[ec]; dn_n = ei[(size_t)E + ec];
      const u16* Dp = wsE + (size_t)dn_n*512 + kg*8;
      dA0 = *reinterpret_cast<const uint4*>(Dp +  0);
      dA1 = *reinterpret_cast<const uint4*>(Dp + 32);
      dA2 = *reinterpret_cast<const uint4*>(Dp + 64);
      dA3 = *reinterpret_cast<const uint4*>(Dp + 96);
    }

    // ---- TP combine (dst rows from prefetch, src rows loaded now) ----
    float As[8], Av0[8], Av1[8], Av2[8], b[8], acc[8], t[8];
    cv8(cA0, As); cv8(cA1, Av0); cv8(cA2, Av1); cv8(cA3, Av2);

    const u16* S = wsE + (size_t)sn*512 + kg*8;
    bf16x8 tA[4];
    ld8h(S + 256, b);
#pragma unroll
    for (int j = 0; j < 8; ++j) t[j] = As[j]*b[j];
    ld8h(S + 288, b);
#pragma unroll
    for (int j = 0; j < 8; ++j) acc[j] = Av0[j]*b[j];
    ld8h(S + 320, b);
#pragma unroll
    for (int j = 0; j < 8; ++j) acc[j] = __builtin_fmaf(Av1[j], b[j], acc[j]);
    ld8h(S + 352, b);
#pragma unroll
    for (int j = 0; j < 8; ++j) acc[j] = __builtin_fmaf(Av2[j], b[j], acc[j]);
#pragma unroll
    for (int j = 0; j < 8; ++j) t[j] = __builtin_fmaf(acc[j], INV_S3, t[j]);
    tA[0] = cvt8(t);

    ld8h(S + 480, acc);                         // B3
    ld8h(S + 384, b);
#pragma unroll
    for (int j = 0; j < 8; ++j) t[j] = As[j]*b[j] + Av0[j]*acc[j];
    tA[1] = cvt8(t);
    ld8h(S + 416, b);
#pragma unroll
    for (int j = 0; j < 8; ++j) t[j] = As[j]*b[j] + Av1[j]*acc[j];
    tA[2] = cvt8(t);
    ld8h(S + 448, b);
#pragma unroll
    for (int j = 0; j < 8; ++j) t[j] = As[j]*b[j] + Av2[j]*acc[j];
    tA[3] = cvt8(t);

    // ---- resblock res_w[1] (inline; weights pre-scaled) ----
    f32x4 c1[8], co[8];
#pragma unroll
    for (int i = 0; i < 8; ++i) { c1[i] = zero4; co[i] = zero4; }
#pragma unroll
    for (int rt = 0; rt < 4; ++rt) {
#pragma unroll
      for (int ct = 0; ct < 2; ++ct) {
        c1[rt*2+ct] = mfma16(tA[rt], rt==0 ? Bs1[ct] : Bv1[ct], c1[rt*2+ct]);
        co[rt*2+ct] = mfma16(tA[rt], rt==0 ? Bsks[ct] : Bskv[ct], co[rt*2+ct]);
      }
    }

#pragma unroll
    for (int ct = 0; ct < 2; ++ct)
#pragma unroll
      for (int i = 0; i < 4; ++i)
        wbuf[(kg*4 + i)*36 + ct*16 + col] = c1[ct][i];
    float ag[8];
    *reinterpret_cast<float4*>(&ag[0]) = *reinterpret_cast<const float4*>(&wbuf[col*36 + kg*8]);
    *reinterpret_cast<float4*>(&ag[4]) = *reinterpret_cast<const float4*>(&wbuf[col*36 + kg*8 + 4]);
    bf16x8 Ag = cvt8(ag);
    f32x4 cg0 = mfma16(Ag, Bg[0], zero4);
    f32x4 cg1 = mfma16(Ag, Bg[1], zero4);
    float g0[4], g1[4];
#pragma unroll
    for (int i = 0; i < 4; ++i) {
      g0[i] = sigmoidf(cg0[i]);
      g1[i] = sigmoidf(cg1[i]);
    }

#pragma unroll
    for (int ct = 0; ct < 2; ++ct)
#pragma unroll
      for (int i = 0; i < 4; ++i) {
        float v = c1[ct][i];
        c1[ct][i] = v * sigmoidf(v);
      }
#pragma unroll
    for (int rt = 1; rt < 4; ++rt)
#pragma unroll
      for (int ct = 0; ct < 2; ++ct)
#pragma unroll
        for (int i = 0; i < 4; ++i)
          c1[rt*2+ct][i] *= (ct == 0 ? g0[i] : g1[i]);

#pragma unroll
    for (int rt = 0; rt < 4; ++rt)
#pragma unroll
      for (int ct = 0; ct < 2; ++ct)
#pragma unroll
        for (int i = 0; i < 4; ++i)
          wbuf[(rt*16 + kg*4 + i)*36 + ct*16 + col] = c1[rt*2+ct][i];
    bf16x8 t2A[4];
#pragma unroll
    for (int rt = 0; rt < 4; ++rt) {
      float a8[8];
      *reinterpret_cast<float4*>(&a8[0]) = *reinterpret_cast<const float4*>(&wbuf[(rt*16+col)*36 + kg*8]);
      *reinterpret_cast<float4*>(&a8[4]) = *reinterpret_cast<const float4*>(&wbuf[(rt*16+col)*36 + kg*8 + 4]);
      t2A[rt] = cvt8(a8);
    }

#pragma unroll
    for (int rt = 0; rt < 4; ++rt)
#pragma unroll
      for (int ct = 0; ct < 2; ++ct)
        co[rt*2+ct] = mfma16(t2A[rt], rt==0 ? Bl2s[ct] : Bl2v[ct], co[rt*2+ct]);

    // ---- epilogue: C -> rows, +R, store ----
#pragma unroll
    for (int rt = 0; rt < 4; ++rt)
#pragma unroll
      for (int ct = 0; ct < 2; ++ct)
#pragma unroll
        for (int i = 0; i < 4; ++i)
          wbuf[(rt*16 + kg*4 + i)*33 + ct*16 + col] = co[rt*2+ct][i];

    const int eloc = lane >> 2, comp = lane & 3;
    float o[32];
    {
      const float* rp = &wbuf[(comp*16 + eloc)*33];
#pragma unroll
      for (int m = 0; m < 32; ++m) o[m] = rp[m];
    }
    int e2 = ctile*16 + eloc;
    int ec2 = (e2 < E) ? e2 : (E - 1);
    int dn2 = ei[(size_t)E + ec2];
    {
      float r[32];
      ld32h(wsE + (size_t)dn2*512 + 128 + comp*32, r);
#pragma unroll
      for (int c = 0; c < 32; ++c) o[c] += r[c];
    }
    if (comp == 0) {
      if (e2 < E) st32f(offs + (size_t)e2*32, o);
    } else {
#pragma unroll
      for (int c = 0; c < 32; ++c) wbuf[eloc*97 + 3*c + (comp-1)] = o[c];
    }
    {
      const size_t obase = (size_t)ctile * 1536;
#pragma unroll
      for (int i = 0; i < 6; ++i) {
        int s = i*64 + lane;
        int row = s / 24, c4 = s - row*24;
        const float* sp = &wbuf[row*97 + c4*4];
        float4 q; q.x = sp[0]; q.y = sp[1]; q.z = sp[2]; q.w = sp[3];
        if (ctile*16 + row < E)
          *reinterpret_cast<float4*>(offv + obase + (size_t)s*4) = q;
      }
    }

    if (tile >= ntE) break;
  }
}

extern "C" void kernel_launch(void* const* d_in, const int* in_sizes, int n_in,
                              void* d_out, int out_size, void* d_ws, size_t ws_size,
                              hipStream_t stream) {
  const float* node_s = (const float*)d_in[0];
  const float* node_v = (const float*)d_in[1];
  const float* tpw    = (const float*)d_in[2];
  const float* resw   = (const float*)d_in[3];
  const int*   ei     = (const int*)d_in[4];
  const int N = in_sizes[0] / 32;
  const int E = in_sizes[4] / 2;

  float* out  = (float*)d_out;
  float* dgs  = out;
  float* dgv  = out + (size_t)N*32;
  float* offs = out + (size_t)N*128;
  float* offv = offs + (size_t)E*32;

  u16* wsE = (u16*)d_ws;               // N*512 bf16 (edge-read data)
  u16* wsD = wsE + (size_t)N*512;      // N*512 bf16 (diag data)

  const int ntN = (N + 15) / 16;
  const int ntE = (E + 15) / 16;

  const int aBlocks = (6*ntN + 3) / 4;
  const int bBlocks = (ntN + 3) / 4;
  int egB = (ntE + 3) / 4; if (egB > 4096) egB = 4096;

  nodeA_kernel<<<aBlocks, 256, 0, stream>>>(node_s, node_v, tpw, resw,
                                            wsE, wsD, N, ntN);
  edgeB_kernel<<<egB + bBlocks, 256, 0, stream>>>(ei, resw, wsE, wsD,
                                                  offs, offv, dgs, dgv,
                                                  E, ntE, N, ntN, egB);
}